// Round 4
// baseline (548.823 us; speedup 1.0000x reference)
//
#include <hip/hip_runtime.h>
#include <hip/hip_cooperative_groups.h>

namespace cg = cooperative_groups;

#define N_S   65536
#define DXF   1024
#define DD    256
#define NM1   65535.0f
#define EPSR  0.001f

typedef __attribute__((ext_vector_type(4)))  float          f32x4;
typedef __attribute__((ext_vector_type(16))) float          f32x16;
typedef __attribute__((ext_vector_type(8)))  short          bf16x8;
typedef __attribute__((ext_vector_type(4)))  unsigned short ushort4_t;
typedef __attribute__((ext_vector_type(8)))  unsigned short ushort8_t;

__device__ __forceinline__ unsigned short f2bf(float f){
  unsigned u = __float_as_uint(f);
  u += 0x7fffu + ((u >> 16) & 1u);   // RNE
  return (unsigned short)(u >> 16);
}
__device__ __forceinline__ float bf2f(unsigned short h){
  return __uint_as_float(((unsigned)h) << 16);
}
__device__ __forceinline__ f32x4 mfma16(bf16x8 a, bf16x8 b, f32x4 c){
  return __builtin_amdgcn_mfma_f32_16x16x32_bf16(a, b, c, 0, 0, 0);
}
__device__ __forceinline__ f32x16 mfma32(bf16x8 a, bf16x8 b, f32x16 c){
  return __builtin_amdgcn_mfma_f32_32x32x16_bf16(a, b, c, 0, 0, 0);
}
__device__ __forceinline__ void gld_lds16(const void* g, void* l){
  __builtin_amdgcn_global_load_lds(
      (const __attribute__((address_space(1))) unsigned int*)g,
      (__attribute__((address_space(3))) unsigned int*)l, 16, 0, 0);
}
__device__ __forceinline__ bf16x8 pack8(float4 a, float4 b){
  union { unsigned u[4]; bf16x8 v; } r;
  asm("v_cvt_pk_bf16_f32 %0, %1, %2" : "=v"(r.u[0]) : "v"(a.x), "v"(a.y));
  asm("v_cvt_pk_bf16_f32 %0, %1, %2" : "=v"(r.u[1]) : "v"(a.z), "v"(a.w));
  asm("v_cvt_pk_bf16_f32 %0, %1, %2" : "=v"(r.u[2]) : "v"(b.x), "v"(b.y));
  asm("v_cvt_pk_bf16_f32 %0, %1, %2" : "=v"(r.u[3]) : "v"(b.z), "v"(b.w));
  return r.v;
}

// ---------------- W'^T build + zero accumulators ---------------------------
__global__ void k_prep(const float* __restrict__ Wx, const float* __restrict__ Wy,
                       const float* __restrict__ mux, const float* __restrict__ muy,
                       unsigned short* __restrict__ WTx, unsigned short* __restrict__ WTy,
                       float* __restrict__ sx, float* __restrict__ sy,
                       float* __restrict__ scal){
  int v = blockIdx.y;
  const float* W  = v ? Wy  : Wx;
  const float* mu = v ? muy : mux;
  unsigned short* WT = v ? WTy : WTx;
  int j = threadIdx.x;
  if (blockIdx.x == 0){
    (v ? sy : sx)[j] = 0.f;
    if (v == 0 && j < 5) scal[2 + j] = 0.f;   // regx, regy, trace, normA, normB
  }
  #pragma unroll
  for (int r = 0; r < 4; ++r){
    int k = blockIdx.x * 4 + r;
    float g = fminf(fmaxf(mu[k] + 0.5f, 0.f), 1.f);
    WT[(size_t)j * DXF + k] = f2bf(g * W[(size_t)k * DD + j]);
  }
}

// ---------------- big GEMM: Xh = X @ W'  -> bf16 ---------------------------
// block 256 thr (4 waves 2x2), tile 64x256; wave tile 32x128; 32x32x16 MFMA.
// A: fp32 K=64 panels via global_load_lds, source-XOR-swizzled, dbuf.
// B: bf16 K=32 substeps via global_load_lds, [chunk][col] layout, dbuf.
// All VMEM = global_load_lds -> hand-counted vmcnt, 1 raw barrier/substep.
__global__ __launch_bounds__(256, 2) void k_gemm4(
    const float* __restrict__ X, const float* __restrict__ Y,
    const unsigned short* __restrict__ WTx, const unsigned short* __restrict__ WTy,
    unsigned short* __restrict__ Xhb, unsigned short* __restrict__ Yhb){
  const float* A = blockIdx.z ? Y : X;
  const unsigned short* WT = blockIdx.z ? WTy : WTx;
  unsigned short* Out = blockIdx.z ? Yhb : Xhb;

  __shared__ float          aLds[2][64][64];      // 32KB fp32 A panels
  __shared__ unsigned short bLds[2][4][256][8];   // 32KB bf16 B substeps

  int tid = threadIdx.x, lane = tid & 63, wid = tid >> 6;
  int wr = wid >> 1, wc = wid & 1;
  int row0 = blockIdx.x * 64;

  f32x16 acc[4] = {};

  // A stage: instr i -> rows wid*16+i*4+(lane>>4); slot c=lane&15 holds chunk c^(row&7)
  int ar_row = wid * 16 + (lane >> 4);
  int ar_sl  = lane & 15;
  const float* abase = A + (size_t)(row0 + ar_row) * DXF;
  // B stage: instr i = k-chunk; col = wid*64 + lane
  const unsigned short* bbase = WT + (size_t)(wid * 64 + lane) * DXF;

  auto stageA = [&](int buf, int p){
    #pragma unroll
    for (int i = 0; i < 4; ++i){
      int r = ar_row + i * 4;
      const float* src = abase + (size_t)(i * 4) * DXF + p * 64 + ((ar_sl ^ (r & 7)) << 2);
      gld_lds16((const void*)src, (void*)&aLds[buf][wid * 16 + i * 4][0]);
    }
  };
  auto stageB = [&](int buf, int g){
    #pragma unroll
    for (int i = 0; i < 4; ++i){
      const unsigned short* src = bbase + g * 32 + i * 8;
      gld_lds16((const void*)src, (void*)&bLds[buf][i][wid * 64][0]);
    }
  };

  int arow_l = wr * 32 + (lane & 31);
  int rx7 = arow_l & 7;
  int lh = lane >> 5;

  stageB(0, 0);
  stageA(0, 0);
  for (int g = 0; g < 32; ++g){
    int p = g >> 1, s = g & 1;
    if (s && g < 31) asm volatile("s_waitcnt vmcnt(4)" ::: "memory");
    else             asm volatile("s_waitcnt vmcnt(0)" ::: "memory");
    __builtin_amdgcn_s_barrier();
    if (g + 1 < 32) stageB((g + 1) & 1, g + 1);
    if (s == 0 && p + 1 < 16) stageA((p + 1) & 1, p + 1);

    const float* al = &aLds[p & 1][arow_l][0];
    int c0 = s * 8 + lh * 2;
    float4 a0 = *(const float4*)(al + (((c0    ) ^ rx7) << 2));
    float4 a1 = *(const float4*)(al + (((c0 + 1) ^ rx7) << 2));
    float4 a2 = *(const float4*)(al + (((c0 + 4) ^ rx7) << 2));
    float4 a3 = *(const float4*)(al + (((c0 + 5) ^ rx7) << 2));
    bf16x8 af0 = pack8(a0, a1);
    bf16x8 af1 = pack8(a2, a3);
    int gb = g & 1;
    #pragma unroll
    for (int ni = 0; ni < 4; ++ni){
      int col = wc * 128 + ni * 32 + (lane & 31);
      bf16x8 b0 = *(const bf16x8*)&bLds[gb][lh][col][0];
      bf16x8 b1 = *(const bf16x8*)&bLds[gb][2 + lh][col][0];
      acc[ni] = mfma32(af0, b0, acc[ni]);
      acc[ni] = mfma32(af1, b1, acc[ni]);
    }
  }

  // epilogue: LDS transpose (reuse aLds, 32KB = 64x256 bf16) -> coalesced stores
  __syncthreads();
  unsigned short* ol = (unsigned short*)&aLds[0][0][0];
  #pragma unroll
  for (int ni = 0; ni < 4; ++ni){
    int col = wc * 128 + ni * 32 + (lane & 31);
    #pragma unroll
    for (int reg = 0; reg < 16; ++reg){
      int row = wr * 32 + (reg & 3) + ((reg >> 2) << 3) + ((lane >> 5) << 2);
      ol[row * 256 + col] = f2bf(acc[ni][reg]);
    }
  }
  __syncthreads();
  unsigned short* ob = Out + (size_t)row0 * DD;
  #pragma unroll
  for (int r = 0; r < 8; ++r){
    int off = r * 2048 + tid * 8;
    *(ushort8_t*)(ob + off) = *(const ushort8_t*)(ol + off);
  }
}

// ---------------- Gram kernel: split-K partials ----------------------------
__global__ __launch_bounds__(512) void k_gram(
    const unsigned short* __restrict__ Xhb, const unsigned short* __restrict__ Yhb,
    float* __restrict__ part, float* __restrict__ sx, float* __restrict__ sy, int P){
  int type = blockIdx.z;                   // 0:xx 1:yy 2:yx
  int p = blockIdx.x;
  int chunk = N_S / P;
  int r0 = p * chunk;
  const unsigned short* Asrc = (type == 0) ? Xhb : Yhb;
  const unsigned short* Bsrc = (type == 1) ? Yhb : Xhb;
  bool dualB = (type == 2);

  __shared__ unsigned short At[256][40];
  __shared__ unsigned short Bt[256][40];

  int tid = threadIdx.x;
  int lane = tid & 63, wid = tid >> 6;
  int wr = wid >> 1, wc = wid & 1;

  f32x4 acc[4][8] = {};
  float cs0 = 0.f, cs1 = 0.f;

  int cp  = tid & 127;
  int kb0 = tid >> 7;

  unsigned ua[2][4], ub[2][4];

  auto loadT = [&](int ks){
    int base = r0 + ks * 32;
    #pragma unroll
    for (int r = 0; r < 2; ++r){
      int kb = kb0 + r * 4;
      #pragma unroll
      for (int kr = 0; kr < 4; ++kr){
        ua[r][kr] = *(const unsigned*)(Asrc + (size_t)(base + kb * 4 + kr) * DD + cp * 2);
        if (dualB)
          ub[r][kr] = *(const unsigned*)(Bsrc + (size_t)(base + kb * 4 + kr) * DD + cp * 2);
      }
    }
  };
  auto storeT = [&](){
    #pragma unroll
    for (int r = 0; r < 2; ++r){
      int kb = kb0 + r * 4;
      ushort4_t lo = { (unsigned short)ua[r][0], (unsigned short)ua[r][1],
                       (unsigned short)ua[r][2], (unsigned short)ua[r][3] };
      ushort4_t hi = { (unsigned short)(ua[r][0] >> 16), (unsigned short)(ua[r][1] >> 16),
                       (unsigned short)(ua[r][2] >> 16), (unsigned short)(ua[r][3] >> 16) };
      *(ushort4_t*)&At[cp * 2][kb * 4]     = lo;
      *(ushort4_t*)&At[cp * 2 + 1][kb * 4] = hi;
      if (type < 2){
        #pragma unroll
        for (int kr = 0; kr < 4; ++kr){
          cs0 += bf2f((unsigned short)ua[r][kr]);
          cs1 += bf2f((unsigned short)(ua[r][kr] >> 16));
        }
      }
      if (dualB){
        ushort4_t lob = { (unsigned short)ub[r][0], (unsigned short)ub[r][1],
                          (unsigned short)ub[r][2], (unsigned short)ub[r][3] };
        ushort4_t hib = { (unsigned short)(ub[r][0] >> 16), (unsigned short)(ub[r][1] >> 16),
                          (unsigned short)(ub[r][2] >> 16), (unsigned short)(ub[r][3] >> 16) };
        *(ushort4_t*)&Bt[cp * 2][kb * 4]     = lob;
        *(ushort4_t*)&Bt[cp * 2 + 1][kb * 4] = hib;
      }
    }
  };

  unsigned short (*Btp)[40] = dualB ? Bt : At;

  int KS = chunk / 32;
  loadT(0);
  for (int ks = 0; ks < KS; ++ks){
    __syncthreads();
    storeT();
    __syncthreads();
    if (ks + 1 < KS) loadT(ks + 1);
    bf16x8 af[4], bfv[8];
    #pragma unroll
    for (int mi = 0; mi < 4; ++mi)
      af[mi] = *(const bf16x8*)&At[wr * 64 + mi * 16 + (lane & 15)][(lane >> 4) * 8];
    #pragma unroll
    for (int ni = 0; ni < 8; ++ni)
      bfv[ni] = *(const bf16x8*)&Btp[wc * 128 + ni * 16 + (lane & 15)][(lane >> 4) * 8];
    #pragma unroll
    for (int mi = 0; mi < 4; ++mi)
      #pragma unroll
      for (int ni = 0; ni < 8; ++ni)
        acc[mi][ni] = mfma16(af[mi], bfv[ni], acc[mi][ni]);
  }

  float* dst = part + ((size_t)p * 3 + type) * 65536;
  #pragma unroll
  for (int mi = 0; mi < 4; ++mi)
    #pragma unroll
    for (int ni = 0; ni < 8; ++ni)
      #pragma unroll
      for (int rr = 0; rr < 4; ++rr){
        int grow = wr * 64 + mi * 16 + (lane >> 4) * 4 + rr;
        int gcol = wc * 128 + ni * 16 + (lane & 15);
        dst[(size_t)grow * 256 + gcol] = acc[mi][ni][rr];
      }

  if (type < 2){
    __syncthreads();
    float* red = (float*)&At[0][0];
    red[kb0 * 256 + cp * 2]     = cs0;
    red[kb0 * 256 + cp * 2 + 1] = cs1;
    __syncthreads();
    if (tid < 256){
      float s = red[tid] + red[256 + tid] + red[512 + tid] + red[768 + tid];
      atomicAdd((type == 0 ? sx : sy) + tid, s);
    }
  }
}

// ---------------- reduce partials -> A, B (fp32 + bf16), Cyx bf16 (+T) -----
__global__ void k_reduce(const float* __restrict__ part, const float* __restrict__ sx,
                         const float* __restrict__ sy, float* __restrict__ Am,
                         float* __restrict__ Bm,
                         unsigned short* __restrict__ Abf, unsigned short* __restrict__ Bbf,
                         unsigned short* __restrict__ Cbf, unsigned short* __restrict__ CbfT,
                         int P){
  int i = blockIdx.x, j = threadIdx.x;
  size_t idx = (size_t)i * 256 + j;
  float gxx = 0.f, gyy = 0.f, gyx = 0.f;
  for (int p = 0; p < P; ++p){
    const float* b = part + (size_t)p * 3 * 65536;
    gxx += b[idx];
    gyy += b[65536 + idx];
    gyx += b[131072 + idx];
  }
  float invn1 = 1.f / NM1;
  float invn  = 1.f / (float)N_S;
  float sxi = sx[i], sxj = sx[j], syi = sy[i], syj = sy[j];
  float diag = (i == j) ? 1.f : 0.f;
  float am = (gyy - syi * syj * invn) * invn1 + diag * (2.f * EPSR);
  float bm = (gxx - sxi * sxj * invn) * invn1 + diag * EPSR;
  float cv = (gyx - syi * sxj * invn) * invn1;
  Am[idx] = am;  Bm[idx] = bm;
  Abf[idx] = f2bf(am);
  Bbf[idx] = f2bf(bm);
  Cbf[idx] = f2bf(cv);
  CbfT[(size_t)j * 256 + i] = f2bf(cv);
}

// ---------------- cooperative tail: norms+regs, init, 8x NS, U/V, trace ----
__device__ __forceinline__ f32x4 ns_tile(const unsigned short* __restrict__ Ar,
                                         const unsigned short* __restrict__ Br,
                                         int rt, int ct, int lane){
  const unsigned short* ap = Ar + (size_t)(rt * 16 + (lane & 15)) * 256 + ((lane >> 4) << 3);
  const unsigned short* bp = Br + (size_t)(ct * 16 + (lane & 15)) * 256 + ((lane >> 4) << 3);
  f32x4 acc = {};
  #pragma unroll
  for (int kb = 0; kb < 8; ++kb){
    bf16x8 a = *(const bf16x8*)(ap + kb * 32);
    bf16x8 b = *(const bf16x8*)(bp + kb * 32);
    acc = mfma16(a, b, acc);
  }
  return acc;
}

__global__ __launch_bounds__(512) void k_ns(
    const float* __restrict__ Am, const float* __restrict__ Bm,
    const unsigned short* __restrict__ Abf, const unsigned short* __restrict__ Bbf,
    const unsigned short* __restrict__ Cbf, const unsigned short* __restrict__ CbfT,
    unsigned short* __restrict__ X0, unsigned short* __restrict__ X1,
    unsigned short* __restrict__ Tb, float* __restrict__ U, float* __restrict__ V,
    float* __restrict__ scal, float* __restrict__ out,
    const float* __restrict__ mux, const float* __restrict__ muy){
  cg::grid_group grid = cg::this_grid();
  __shared__ float red[512];
  int bid = blockIdx.x, tid = threadIdx.x;
  int lane = tid & 63, wid = tid >> 6;
  unsigned* su = (unsigned*)scal;

  // phase 0: inf-norms (A: blocks 0-31, B: blocks 32-63), one row per wave
  {
    int mat = bid >> 5;
    int row = (bid & 31) * 8 + wid;
    const float* M = mat ? Bm : Am;
    float s = 0.f;
    #pragma unroll
    for (int j = 0; j < 4; ++j) s += fabsf(M[(size_t)row * 256 + j * 64 + lane]);
    #pragma unroll
    for (int o = 32; o > 0; o >>= 1) s += __shfl_xor(s, o);
    if (lane == 0) atomicMax(su + 5 + mat, __float_as_uint(s));
  }
  // STG regularizers on blocks 0,1
  if (bid < 2){
    const float* mu = bid ? muy : mux;
    float a = 0.5f * (1.f + erff(mu[tid]       * 1.41421356237f));
    float b = 0.5f * (1.f + erff(mu[tid + 512] * 1.41421356237f));
    red[tid] = a + b;
    __syncthreads();
    for (int st = 256; st > 0; st >>= 1){ if (tid < st) red[tid] += red[tid + st]; __syncthreads(); }
    if (tid == 0) atomicAdd(scal + 2 + bid, 0.1f * red[0] / 1024.f);
  }
  grid.sync();

  // phase 1: X0 = alpha * I (bf16), both matrices
  float aa = 1.f / __uint_as_float(su[5]);
  float ab = 1.f / __uint_as_float(su[6]);
  #pragma unroll
  for (int r = 0; r < 4; ++r){
    int idx = (bid * 512 + tid) + r * 32768;
    int mat = idx >> 16, e = idx & 65535;
    X0[idx] = ((e >> 8) == (e & 255)) ? f2bf(mat ? ab : aa) : (unsigned short)0;
  }
  grid.sync();

  int wave = bid * 8 + wid;                 // 0..511, one 16x16 tile each
  int mat = wave >> 8, rt = (wave >> 4) & 15, ct = wave & 15;
  unsigned short *Xc = X0, *Xn = X1;

  for (int it = 0; it < 8; ++it){
    {
      const unsigned short* M = mat ? Bbf : Abf;
      f32x4 a4 = ns_tile(M, Xc + mat * 65536, rt, ct, lane);
      int col = ct * 16 + (lane & 15);
      #pragma unroll
      for (int rr = 0; rr < 4; ++rr){
        int row = rt * 16 + (lane >> 4) * 4 + rr;
        Tb[mat * 65536 + row * 256 + col] = f2bf(a4[rr]);
      }
    }
    grid.sync();
    {
      f32x4 a4 = ns_tile(Xc + mat * 65536, Tb + mat * 65536, rt, ct, lane);
      int col = ct * 16 + (lane & 15);
      #pragma unroll
      for (int rr = 0; rr < 4; ++rr){
        int row = rt * 16 + (lane >> 4) * 4 + rr;
        size_t o = (size_t)mat * 65536 + row * 256 + col;
        Xn[o] = f2bf(2.f * bf2f(Xc[o]) - a4[rr]);
      }
    }
    grid.sync();
    unsigned short* t2 = Xc; Xc = Xn; Xn = t2;
  }

  // U = XA @ Cyx, V = XB @ Cyx^T
  {
    f32x4 a4 = ns_tile(Xc + mat * 65536, mat ? Cbf : CbfT, rt, ct, lane);
    float* D = mat ? V : U;
    int col = ct * 16 + (lane & 15);
    #pragma unroll
    for (int rr = 0; rr < 4; ++rr){
      int row = rt * 16 + (lane >> 4) * 4 + rr;
      D[row * 256 + col] = a4[rr];
    }
  }
  grid.sync();

  // trace(U @ V)
  float tr = 0.f;
  #pragma unroll
  for (int r = 0; r < 2; ++r){
    int idx = bid * 1024 + r * 512 + tid;
    int i = idx >> 8, j = idx & 255;
    tr += U[idx] * V[j * 256 + i];
  }
  red[tid] = tr;
  __syncthreads();
  for (int s2 = 256; s2 > 0; s2 >>= 1){ if (tid < s2) red[tid] += red[tid + s2]; __syncthreads(); }
  if (tid == 0) atomicAdd(scal + 4, red[0]);
  grid.sync();
  if (bid == 0 && tid == 0)
    out[0] = -scal[4] / 256.f + scal[2] + scal[3];
}

extern "C" void kernel_launch(void* const* d_in, const int* in_sizes, int n_in,
                              void* d_out, int out_size, void* d_ws, size_t ws_size,
                              hipStream_t stream){
  (void)in_sizes; (void)n_in; (void)out_size;
  const float* X   = (const float*)d_in[0];
  const float* Y   = (const float*)d_in[1];
  const float* mux = (const float*)d_in[2];
  const float* muy = (const float*)d_in[3];
  const float* Wx  = (const float*)d_in[4];
  const float* Wy  = (const float*)d_in[6];
  float* out = (float*)d_out;
  char* ws = (char*)d_ws;

  const size_t MB = 1ull << 20;
  const size_t KB = 1024;
  size_t oXHB = 0;
  size_t oYHB = 32 * MB;
  size_t oWTX = 64 * MB;
  size_t oWTY = oWTX + 512 * KB;
  size_t oSX  = oWTY + 512 * KB;
  size_t oSY  = oSX + 4 * KB;
  size_t oSC  = oSY + 4 * KB;
  size_t oA   = oSC + 4 * KB;
  size_t oB   = oA   + 256 * KB;
  size_t oABF = oB   + 256 * KB;
  size_t oBBF = oABF + 128 * KB;
  size_t oCBF = oBBF + 128 * KB;
  size_t oCBT = oCBF + 128 * KB;
  size_t oX0  = oCBT + 128 * KB;
  size_t oX1  = oX0  + 256 * KB;
  size_t oTB  = oX1  + 256 * KB;
  size_t oU   = oTB  + 256 * KB;
  size_t oV   = oU   + 256 * KB;
  size_t oPart = 68 * MB;

  size_t per = 3ull * 65536 * 4;
  int P = 64;
  while (P > 8 && oPart + (size_t)P * per > ws_size) P >>= 1;

  unsigned short* Xhb = (unsigned short*)(ws + oXHB);
  unsigned short* Yhb = (unsigned short*)(ws + oYHB);
  unsigned short* WTx = (unsigned short*)(ws + oWTX);
  unsigned short* WTy = (unsigned short*)(ws + oWTY);
  float* sx   = (float*)(ws + oSX);
  float* sy   = (float*)(ws + oSY);
  float* scal = (float*)(ws + oSC);
  float* Am   = (float*)(ws + oA);
  float* Bm   = (float*)(ws + oB);
  unsigned short* Abf  = (unsigned short*)(ws + oABF);
  unsigned short* Bbf  = (unsigned short*)(ws + oBBF);
  unsigned short* Cbf  = (unsigned short*)(ws + oCBF);
  unsigned short* CbfT = (unsigned short*)(ws + oCBT);
  unsigned short* X0   = (unsigned short*)(ws + oX0);
  unsigned short* X1   = (unsigned short*)(ws + oX1);
  unsigned short* Tb   = (unsigned short*)(ws + oTB);
  float* U    = (float*)(ws + oU);
  float* V    = (float*)(ws + oV);
  float* part = (float*)(ws + oPart);

  k_prep<<<dim3(256, 2), 256, 0, stream>>>(Wx, Wy, mux, muy, WTx, WTy, sx, sy, scal);
  k_gemm4<<<dim3(1024, 1, 2), 256, 0, stream>>>(X, Y, WTx, WTy, Xhb, Yhb);
  k_gram<<<dim3(P, 1, 3), 512, 0, stream>>>(Xhb, Yhb, part, sx, sy, P);
  k_reduce<<<256, 256, 0, stream>>>(part, sx, sy, Am, Bm, Abf, Bbf, Cbf, CbfT, P);

  void* args[] = { (void*)&Am, (void*)&Bm, (void*)&Abf, (void*)&Bbf,
                   (void*)&Cbf, (void*)&CbfT, (void*)&X0, (void*)&X1,
                   (void*)&Tb, (void*)&U, (void*)&V, (void*)&scal, (void*)&out,
                   (void*)&mux, (void*)&muy };
  hipLaunchCooperativeKernel((const void*)k_ns, dim3(64), dim3(512), args, 0, stream);
}

// Round 5
// 508.489 us; speedup vs baseline: 1.0793x; 1.0793x over previous
//
#include <hip/hip_runtime.h>
#include <hip/hip_cooperative_groups.h>

namespace cg = cooperative_groups;

#define N_S   65536
#define DXF   1024
#define DD    256
#define NM1   65535.0f
#define EPSR  0.001f

typedef __attribute__((ext_vector_type(4)))  float          f32x4;
typedef __attribute__((ext_vector_type(16))) float          f32x16;
typedef __attribute__((ext_vector_type(8)))  short          bf16x8;
typedef __attribute__((ext_vector_type(4)))  unsigned short ushort4_t;
typedef __attribute__((ext_vector_type(8)))  unsigned short ushort8_t;

__device__ __forceinline__ unsigned short f2bf(float f){
  unsigned u = __float_as_uint(f);
  u += 0x7fffu + ((u >> 16) & 1u);   // RNE
  return (unsigned short)(u >> 16);
}
__device__ __forceinline__ float bf2f(unsigned short h){
  return __uint_as_float(((unsigned)h) << 16);
}
__device__ __forceinline__ f32x4 mfma16(bf16x8 a, bf16x8 b, f32x4 c){
  return __builtin_amdgcn_mfma_f32_16x16x32_bf16(a, b, c, 0, 0, 0);
}
__device__ __forceinline__ void gld_lds16(const void* g, void* l){
  __builtin_amdgcn_global_load_lds(
      (const __attribute__((address_space(1))) unsigned int*)g,
      (__attribute__((address_space(3))) unsigned int*)l, 16, 0, 0);
}
__device__ __forceinline__ bf16x8 pack8(float4 a, float4 b){
  union { unsigned u[4]; bf16x8 v; } r;
  asm("v_cvt_pk_bf16_f32 %0, %1, %2" : "=v"(r.u[0]) : "v"(a.x), "v"(a.y));
  asm("v_cvt_pk_bf16_f32 %0, %1, %2" : "=v"(r.u[1]) : "v"(a.z), "v"(a.w));
  asm("v_cvt_pk_bf16_f32 %0, %1, %2" : "=v"(r.u[2]) : "v"(b.x), "v"(b.y));
  asm("v_cvt_pk_bf16_f32 %0, %1, %2" : "=v"(r.u[3]) : "v"(b.z), "v"(b.w));
  return r.v;
}

// ------- W' in k-chunk-major bf16 layout: WTk[k>>3][col][k&7]  -------------
// (so GEMM B staging is a fully-coalesced global_load_lds)
__global__ void k_prep(const float* __restrict__ Wx, const float* __restrict__ Wy,
                       const float* __restrict__ mux, const float* __restrict__ muy,
                       unsigned short* __restrict__ WTx, unsigned short* __restrict__ WTy,
                       float* __restrict__ sx, float* __restrict__ sy,
                       float* __restrict__ scal){
  int v = blockIdx.y;
  const float* W  = v ? Wy  : Wx;
  const float* mu = v ? muy : mux;
  unsigned short* WT = v ? WTy : WTx;
  int j = threadIdx.x;
  if (blockIdx.x == 0){
    (v ? sy : sx)[j] = 0.f;
    if (v == 0 && j < 5) scal[2 + j] = 0.f;   // regx, regy, trace, normA, normB
  }
  #pragma unroll
  for (int r = 0; r < 4; ++r){
    int k = blockIdx.x * 4 + r;
    float g = fminf(fmaxf(mu[k] + 0.5f, 0.f), 1.f);
    WT[(size_t)(k >> 3) * 2048 + j * 8 + (k & 7)] = f2bf(g * W[(size_t)k * DD + j]);
  }
}

// ---------------- big GEMM: Xh = X @ W'  -> bf16 ---------------------------
// 256 thr (4 waves 2x2), tile 64x256, wave 32x128, 16x16x32 MFMA.
// 4 blocks/CU (37KB LDS, VGPR<=128) -> ~16 waves/CU: TLP hides HBM latency.
// A: float4 global->reg (1-step prefetch) -> cvt_pk -> LDS. B: coalesced
// global_load_lds dbuf from k-chunk-major W'. Counted vmcnt keeps A+B in flight.
__global__ __launch_bounds__(256, 4) void k_gemm5(
    const float* __restrict__ X, const float* __restrict__ Y,
    const unsigned short* __restrict__ WTx, const unsigned short* __restrict__ WTy,
    unsigned short* __restrict__ Xhb, unsigned short* __restrict__ Yhb){
  const float* A = blockIdx.z ? Y : X;
  const unsigned short* WT = blockIdx.z ? WTy : WTx;
  unsigned short* Out = blockIdx.z ? Yhb : Xhb;

  __shared__ unsigned short As[64][40];          // 5KB bf16, pad 40: aligned, 2-way
  __shared__ unsigned short Bs[2][4][256][8];    // 32KB bf16 dbuf, chunk-major

  int tid = threadIdx.x, lane = tid & 63, wid = tid >> 6;
  int wr = wid >> 1, wc = wid & 1;
  int row0 = blockIdx.x * 64;

  f32x4 acc[2][8] = {};

  int s_row = tid >> 2, s_kq = tid & 3;
  const float* ap = A + (size_t)(row0 + s_row) * DXF + s_kq * 8;

  auto stageB = [&](int buf, int ks){
    #pragma unroll
    for (int i = 0; i < 4; ++i)
      gld_lds16(WT + (size_t)(ks * 4 + i) * 2048 + (wid * 64 + lane) * 8,
                &Bs[buf][i][wid * 64][0]);
  };

  float4 a0, a1, n0, n1;
  stageB(0, 0);
  asm volatile("" ::: "memory");
  a0 = *(const float4*)(ap);
  a1 = *(const float4*)(ap + 4);

  for (int ks = 0; ks < 32; ++ks){
    // drain this step's B stage (issued last iter); keep A prefetch in flight
    asm volatile("s_waitcnt vmcnt(2)" ::: "memory");
    __builtin_amdgcn_s_barrier();
    if (ks + 1 < 32){
      stageB((ks + 1) & 1, ks + 1);
      asm volatile("" ::: "memory");
      n0 = *(const float4*)(ap + (ks + 1) * 32);
      n1 = *(const float4*)(ap + (ks + 1) * 32 + 4);
      asm volatile("s_waitcnt vmcnt(6)" ::: "memory");   // drain a_cur only
    } else {
      asm volatile("s_waitcnt vmcnt(0)" ::: "memory");
    }
    *(bf16x8*)&As[s_row][s_kq * 8] = pack8(a0, a1);
    asm volatile("s_waitcnt lgkmcnt(0)" ::: "memory");
    __builtin_amdgcn_s_barrier();

    int bb = ks & 1;
    bf16x8 af0 = *(const bf16x8*)&As[wr * 32 + (lane & 15)][(lane >> 4) * 8];
    bf16x8 af1 = *(const bf16x8*)&As[wr * 32 + 16 + (lane & 15)][(lane >> 4) * 8];
    #pragma unroll
    for (int ni = 0; ni < 8; ++ni){
      bf16x8 bf = *(const bf16x8*)&Bs[bb][lane >> 4][wc * 128 + ni * 16 + (lane & 15)][0];
      acc[0][ni] = mfma16(af0, bf, acc[0][ni]);
      acc[1][ni] = mfma16(af1, bf, acc[1][ni]);
    }
    a0 = n0; a1 = n1;
  }

  // epilogue: 2-pass LDS transpose (16KB of Bs) -> coalesced bf16 stores
  __syncthreads();
  unsigned short* tl = &Bs[0][0][0][0];
  #pragma unroll
  for (int p = 0; p < 2; ++p){
    if (wr == p){
      #pragma unroll
      for (int mi = 0; mi < 2; ++mi)
        #pragma unroll
        for (int ni = 0; ni < 8; ++ni)
          #pragma unroll
          for (int rr = 0; rr < 4; ++rr){
            int r = mi * 16 + (lane >> 4) * 4 + rr;
            int c = wc * 128 + ni * 16 + (lane & 15);
            tl[r * 256 + c] = f2bf(acc[mi][ni][rr]);
          }
    }
    __syncthreads();
    unsigned short* ob = Out + (size_t)(row0 + p * 32) * DD;
    #pragma unroll
    for (int r = 0; r < 4; ++r){
      int off = r * 2048 + tid * 8;
      *(ushort8_t*)(ob + off) = *(const ushort8_t*)(tl + off);
    }
    if (p == 0) __syncthreads();
  }
}

// ---------------- Gram kernel: split-K partials ----------------------------
__global__ __launch_bounds__(512) void k_gram(
    const unsigned short* __restrict__ Xhb, const unsigned short* __restrict__ Yhb,
    float* __restrict__ part, float* __restrict__ sx, float* __restrict__ sy, int P){
  int type = blockIdx.z;                   // 0:xx 1:yy 2:yx
  int p = blockIdx.x;
  int chunk = N_S / P;
  int r0 = p * chunk;
  const unsigned short* Asrc = (type == 0) ? Xhb : Yhb;
  const unsigned short* Bsrc = (type == 1) ? Yhb : Xhb;
  bool dualB = (type == 2);

  __shared__ unsigned short At[256][40];
  __shared__ unsigned short Bt[256][40];

  int tid = threadIdx.x;
  int lane = tid & 63, wid = tid >> 6;
  int wr = wid >> 1, wc = wid & 1;

  f32x4 acc[4][8] = {};
  float cs0 = 0.f, cs1 = 0.f;

  int cp  = tid & 127;
  int kb0 = tid >> 7;

  unsigned ua[2][4], ub[2][4];

  auto loadT = [&](int ks){
    int base = r0 + ks * 32;
    #pragma unroll
    for (int r = 0; r < 2; ++r){
      int kb = kb0 + r * 4;
      #pragma unroll
      for (int kr = 0; kr < 4; ++kr){
        ua[r][kr] = *(const unsigned*)(Asrc + (size_t)(base + kb * 4 + kr) * DD + cp * 2);
        if (dualB)
          ub[r][kr] = *(const unsigned*)(Bsrc + (size_t)(base + kb * 4 + kr) * DD + cp * 2);
      }
    }
  };
  auto storeT = [&](){
    #pragma unroll
    for (int r = 0; r < 2; ++r){
      int kb = kb0 + r * 4;
      ushort4_t lo = { (unsigned short)ua[r][0], (unsigned short)ua[r][1],
                       (unsigned short)ua[r][2], (unsigned short)ua[r][3] };
      ushort4_t hi = { (unsigned short)(ua[r][0] >> 16), (unsigned short)(ua[r][1] >> 16),
                       (unsigned short)(ua[r][2] >> 16), (unsigned short)(ua[r][3] >> 16) };
      *(ushort4_t*)&At[cp * 2][kb * 4]     = lo;
      *(ushort4_t*)&At[cp * 2 + 1][kb * 4] = hi;
      if (type < 2){
        #pragma unroll
        for (int kr = 0; kr < 4; ++kr){
          cs0 += bf2f((unsigned short)ua[r][kr]);
          cs1 += bf2f((unsigned short)(ua[r][kr] >> 16));
        }
      }
      if (dualB){
        ushort4_t lob = { (unsigned short)ub[r][0], (unsigned short)ub[r][1],
                          (unsigned short)ub[r][2], (unsigned short)ub[r][3] };
        ushort4_t hib = { (unsigned short)(ub[r][0] >> 16), (unsigned short)(ub[r][1] >> 16),
                          (unsigned short)(ub[r][2] >> 16), (unsigned short)(ub[r][3] >> 16) };
        *(ushort4_t*)&Bt[cp * 2][kb * 4]     = lob;
        *(ushort4_t*)&Bt[cp * 2 + 1][kb * 4] = hib;
      }
    }
  };

  unsigned short (*Btp)[40] = dualB ? Bt : At;

  int KS = chunk / 32;
  loadT(0);
  for (int ks = 0; ks < KS; ++ks){
    __syncthreads();
    storeT();
    __syncthreads();
    if (ks + 1 < KS) loadT(ks + 1);
    bf16x8 af[4], bfv[8];
    #pragma unroll
    for (int mi = 0; mi < 4; ++mi)
      af[mi] = *(const bf16x8*)&At[wr * 64 + mi * 16 + (lane & 15)][(lane >> 4) * 8];
    #pragma unroll
    for (int ni = 0; ni < 8; ++ni)
      bfv[ni] = *(const bf16x8*)&Btp[wc * 128 + ni * 16 + (lane & 15)][(lane >> 4) * 8];
    #pragma unroll
    for (int mi = 0; mi < 4; ++mi)
      #pragma unroll
      for (int ni = 0; ni < 8; ++ni)
        acc[mi][ni] = mfma16(af[mi], bfv[ni], acc[mi][ni]);
  }

  float* dst = part + ((size_t)p * 3 + type) * 65536;
  #pragma unroll
  for (int mi = 0; mi < 4; ++mi)
    #pragma unroll
    for (int ni = 0; ni < 8; ++ni)
      #pragma unroll
      for (int rr = 0; rr < 4; ++rr){
        int grow = wr * 64 + mi * 16 + (lane >> 4) * 4 + rr;
        int gcol = wc * 128 + ni * 16 + (lane & 15);
        dst[(size_t)grow * 256 + gcol] = acc[mi][ni][rr];
      }

  if (type < 2){
    __syncthreads();
    float* red = (float*)&At[0][0];
    red[kb0 * 256 + cp * 2]     = cs0;
    red[kb0 * 256 + cp * 2 + 1] = cs1;
    __syncthreads();
    if (tid < 256){
      float s = red[tid] + red[256 + tid] + red[512 + tid] + red[768 + tid];
      atomicAdd((type == 0 ? sx : sy) + tid, s);
    }
  }
}

// ---------------- reduce partials -> A, B (fp32 + bf16), Cyx bf16 (+T) -----
__global__ void k_reduce(const float* __restrict__ part, const float* __restrict__ sx,
                         const float* __restrict__ sy, float* __restrict__ Am,
                         float* __restrict__ Bm,
                         unsigned short* __restrict__ Abf, unsigned short* __restrict__ Bbf,
                         unsigned short* __restrict__ Cbf, unsigned short* __restrict__ CbfT,
                         int P){
  int i = blockIdx.x, j = threadIdx.x;
  size_t idx = (size_t)i * 256 + j;
  float gxx = 0.f, gyy = 0.f, gyx = 0.f;
  for (int p = 0; p < P; ++p){
    const float* b = part + (size_t)p * 3 * 65536;
    gxx += b[idx];
    gyy += b[65536 + idx];
    gyx += b[131072 + idx];
  }
  float invn1 = 1.f / NM1;
  float invn  = 1.f / (float)N_S;
  float sxi = sx[i], sxj = sx[j], syi = sy[i], syj = sy[j];
  float diag = (i == j) ? 1.f : 0.f;
  float am = (gyy - syi * syj * invn) * invn1 + diag * (2.f * EPSR);
  float bm = (gxx - sxi * sxj * invn) * invn1 + diag * EPSR;
  float cv = (gyx - syi * sxj * invn) * invn1;
  Am[idx] = am;  Bm[idx] = bm;
  Abf[idx] = f2bf(am);
  Bbf[idx] = f2bf(bm);
  Cbf[idx] = f2bf(cv);
  CbfT[(size_t)j * 256 + i] = f2bf(cv);
}

// ---------------- cooperative tail: norms+regs, init, 8x NS, U/V, trace ----
__device__ __forceinline__ f32x4 ns_tile(const unsigned short* __restrict__ Ar,
                                         const unsigned short* __restrict__ Br,
                                         int rt, int ct, int lane){
  const unsigned short* ap = Ar + (size_t)(rt * 16 + (lane & 15)) * 256 + ((lane >> 4) << 3);
  const unsigned short* bp = Br + (size_t)(ct * 16 + (lane & 15)) * 256 + ((lane >> 4) << 3);
  f32x4 acc = {};
  #pragma unroll
  for (int kb = 0; kb < 8; ++kb){
    bf16x8 a = *(const bf16x8*)(ap + kb * 32);
    bf16x8 b = *(const bf16x8*)(bp + kb * 32);
    acc = mfma16(a, b, acc);
  }
  return acc;
}

__global__ __launch_bounds__(512) void k_ns(
    const float* __restrict__ Am, const float* __restrict__ Bm,
    const unsigned short* __restrict__ Abf, const unsigned short* __restrict__ Bbf,
    const unsigned short* __restrict__ Cbf, const unsigned short* __restrict__ CbfT,
    unsigned short* __restrict__ X0, unsigned short* __restrict__ X1,
    unsigned short* __restrict__ Tb, float* __restrict__ U, float* __restrict__ V,
    float* __restrict__ scal, float* __restrict__ out,
    const float* __restrict__ mux, const float* __restrict__ muy){
  cg::grid_group grid = cg::this_grid();
  __shared__ float red[512];
  int bid = blockIdx.x, tid = threadIdx.x;
  int lane = tid & 63, wid = tid >> 6;
  unsigned* su = (unsigned*)scal;

  // phase 0: inf-norms (A: blocks 0-31, B: blocks 32-63), one row per wave
  {
    int mat = bid >> 5;
    int row = (bid & 31) * 8 + wid;
    const float* M = mat ? Bm : Am;
    float s = 0.f;
    #pragma unroll
    for (int j = 0; j < 4; ++j) s += fabsf(M[(size_t)row * 256 + j * 64 + lane]);
    #pragma unroll
    for (int o = 32; o > 0; o >>= 1) s += __shfl_xor(s, o);
    if (lane == 0) atomicMax(su + 5 + mat, __float_as_uint(s));
  }
  // STG regularizers on blocks 0,1
  if (bid < 2){
    const float* mu = bid ? muy : mux;
    float a = 0.5f * (1.f + erff(mu[tid]       * 1.41421356237f));
    float b = 0.5f * (1.f + erff(mu[tid + 512] * 1.41421356237f));
    red[tid] = a + b;
    __syncthreads();
    for (int st = 256; st > 0; st >>= 1){ if (tid < st) red[tid] += red[tid + st]; __syncthreads(); }
    if (tid == 0) atomicAdd(scal + 2 + bid, 0.1f * red[0] / 1024.f);
  }
  grid.sync();

  // phase 1: X0 = alpha * I (bf16), both matrices
  float aa = 1.f / __uint_as_float(su[5]);
  float ab = 1.f / __uint_as_float(su[6]);
  #pragma unroll
  for (int r = 0; r < 4; ++r){
    int idx = (bid * 512 + tid) + r * 32768;
    int mat = idx >> 16, e = idx & 65535;
    X0[idx] = ((e >> 8) == (e & 255)) ? f2bf(mat ? ab : aa) : (unsigned short)0;
  }
  grid.sync();

  int wave = bid * 8 + wid;                 // 0..511, one 16x16 tile each
  int mat = wave >> 8, rt = (wave >> 4) & 15, ct = wave & 15;
  unsigned short *Xc = X0, *Xn = X1;

  for (int it = 0; it < 8; ++it){
    {
      const unsigned short* M = mat ? Bbf : Abf;
      f32x4 a4 = ns_tile(M, Xc + mat * 65536, rt, ct, lane);
      int col = ct * 16 + (lane & 15);
      #pragma unroll
      for (int rr = 0; rr < 4; ++rr){
        int row = rt * 16 + (lane >> 4) * 4 + rr;
        Tb[mat * 65536 + row * 256 + col] = f2bf(a4[rr]);
      }
    }
    grid.sync();
    {
      f32x4 a4 = ns_tile(Xc + mat * 65536, Tb + mat * 65536, rt, ct, lane);
      int col = ct * 16 + (lane & 15);
      #pragma unroll
      for (int rr = 0; rr < 4; ++rr){
        int row = rt * 16 + (lane >> 4) * 4 + rr;
        size_t o = (size_t)mat * 65536 + row * 256 + col;
        Xn[o] = f2bf(2.f * bf2f(Xc[o]) - a4[rr]);
      }
    }
    grid.sync();
    unsigned short* t2 = Xc; Xc = Xn; Xn = t2;
  }

  // U = XA @ Cyx, V = XB @ Cyx^T
  {
    f32x4 a4 = ns_tile(Xc + mat * 65536, mat ? Cbf : CbfT, rt, ct, lane);
    float* D = mat ? V : U;
    int col = ct * 16 + (lane & 15);
    #pragma unroll
    for (int rr = 0; rr < 4; ++rr){
      int row = rt * 16 + (lane >> 4) * 4 + rr;
      D[row * 256 + col] = a4[rr];
    }
  }
  grid.sync();

  // trace(U @ V)
  float tr = 0.f;
  #pragma unroll
  for (int r = 0; r < 2; ++r){
    int idx = bid * 1024 + r * 512 + tid;
    int i = idx >> 8, j = idx & 255;
    tr += U[idx] * V[j * 256 + i];
  }
  red[tid] = tr;
  __syncthreads();
  for (int s2 = 256; s2 > 0; s2 >>= 1){ if (tid < s2) red[tid] += red[tid + s2]; __syncthreads(); }
  if (tid == 0) atomicAdd(scal + 4, red[0]);
  grid.sync();
  if (bid == 0 && tid == 0)
    out[0] = -scal[4] / 256.f + scal[2] + scal[3];
}

extern "C" void kernel_launch(void* const* d_in, const int* in_sizes, int n_in,
                              void* d_out, int out_size, void* d_ws, size_t ws_size,
                              hipStream_t stream){
  (void)in_sizes; (void)n_in; (void)out_size;
  const float* X   = (const float*)d_in[0];
  const float* Y   = (const float*)d_in[1];
  const float* mux = (const float*)d_in[2];
  const float* muy = (const float*)d_in[3];
  const float* Wx  = (const float*)d_in[4];
  const float* Wy  = (const float*)d_in[6];
  float* out = (float*)d_out;
  char* ws = (char*)d_ws;

  const size_t MB = 1ull << 20;
  const size_t KB = 1024;
  size_t oXHB = 0;
  size_t oYHB = 32 * MB;
  size_t oWTX = 64 * MB;
  size_t oWTY = oWTX + 512 * KB;
  size_t oSX  = oWTY + 512 * KB;
  size_t oSY  = oSX + 4 * KB;
  size_t oSC  = oSY + 4 * KB;
  size_t oA   = oSC + 4 * KB;
  size_t oB   = oA   + 256 * KB;
  size_t oABF = oB   + 256 * KB;
  size_t oBBF = oABF + 128 * KB;
  size_t oCBF = oBBF + 128 * KB;
  size_t oCBT = oCBF + 128 * KB;
  size_t oX0  = oCBT + 128 * KB;
  size_t oX1  = oX0  + 256 * KB;
  size_t oTB  = oX1  + 256 * KB;
  size_t oU   = oTB  + 256 * KB;
  size_t oV   = oU   + 256 * KB;
  size_t oPart = 68 * MB;

  size_t per = 3ull * 65536 * 4;
  int P = 128;
  while (P > 8 && oPart + (size_t)P * per > ws_size) P >>= 1;

  unsigned short* Xhb = (unsigned short*)(ws + oXHB);
  unsigned short* Yhb = (unsigned short*)(ws + oYHB);
  unsigned short* WTx = (unsigned short*)(ws + oWTX);
  unsigned short* WTy = (unsigned short*)(ws + oWTY);
  float* sx   = (float*)(ws + oSX);
  float* sy   = (float*)(ws + oSY);
  float* scal = (float*)(ws + oSC);
  float* Am   = (float*)(ws + oA);
  float* Bm   = (float*)(ws + oB);
  unsigned short* Abf  = (unsigned short*)(ws + oABF);
  unsigned short* Bbf  = (unsigned short*)(ws + oBBF);
  unsigned short* Cbf  = (unsigned short*)(ws + oCBF);
  unsigned short* CbfT = (unsigned short*)(ws + oCBT);
  unsigned short* X0   = (unsigned short*)(ws + oX0);
  unsigned short* X1   = (unsigned short*)(ws + oX1);
  unsigned short* Tb   = (unsigned short*)(ws + oTB);
  float* U    = (float*)(ws + oU);
  float* V    = (float*)(ws + oV);
  float* part = (float*)(ws + oPart);

  k_prep<<<dim3(256, 2), 256, 0, stream>>>(Wx, Wy, mux, muy, WTx, WTy, sx, sy, scal);
  k_gemm5<<<dim3(1024, 1, 2), 256, 0, stream>>>(X, Y, WTx, WTy, Xhb, Yhb);
  k_gram<<<dim3(P, 1, 3), 512, 0, stream>>>(Xhb, Yhb, part, sx, sy, P);
  k_reduce<<<256, 256, 0, stream>>>(part, sx, sy, Am, Bm, Abf, Bbf, Cbf, CbfT, P);

  void* args[] = { (void*)&Am, (void*)&Bm, (void*)&Abf, (void*)&Bbf,
                   (void*)&Cbf, (void*)&CbfT, (void*)&X0, (void*)&X1,
                   (void*)&Tb, (void*)&U, (void*)&V, (void*)&scal, (void*)&out,
                   (void*)&mux, (void*)&muy };
  hipLaunchCooperativeKernel((const void*)k_ns, dim3(64), dim3(512), args, 0, stream);
}

// Round 6
// 345.451 us; speedup vs baseline: 1.5887x; 1.4720x over previous
//
#include <hip/hip_runtime.h>

#define N_S   65536
#define DXF   1024
#define DD    256
#define NM1   65535.0f
#define EPSR  0.001f

typedef __attribute__((ext_vector_type(4)))  float          f32x4;
typedef __attribute__((ext_vector_type(16))) float          f32x16;
typedef __attribute__((ext_vector_type(8)))  short          bf16x8;
typedef __attribute__((ext_vector_type(4)))  unsigned short ushort4_t;
typedef __attribute__((ext_vector_type(8)))  unsigned short ushort8_t;

__device__ __forceinline__ unsigned short f2bf(float f){
  unsigned u = __float_as_uint(f);
  u += 0x7fffu + ((u >> 16) & 1u);   // RNE
  return (unsigned short)(u >> 16);
}
__device__ __forceinline__ float bf2f(unsigned short h){
  return __uint_as_float(((unsigned)h) << 16);
}
__device__ __forceinline__ f32x4 mfma16(bf16x8 a, bf16x8 b, f32x4 c){
  return __builtin_amdgcn_mfma_f32_16x16x32_bf16(a, b, c, 0, 0, 0);
}
__device__ __forceinline__ f32x16 mfma32(bf16x8 a, bf16x8 b, f32x16 c){
  return __builtin_amdgcn_mfma_f32_32x32x16_bf16(a, b, c, 0, 0, 0);
}
__device__ __forceinline__ void gld_lds16(const void* g, void* l){
  __builtin_amdgcn_global_load_lds(
      (const __attribute__((address_space(1))) unsigned int*)g,
      (__attribute__((address_space(3))) unsigned int*)l, 16, 0, 0);
}
__device__ __forceinline__ bf16x8 pack8(float4 a, float4 b){
  union { unsigned u[4]; bf16x8 v; } r;
  asm("v_cvt_pk_bf16_f32 %0, %1, %2" : "=v"(r.u[0]) : "v"(a.x), "v"(a.y));
  asm("v_cvt_pk_bf16_f32 %0, %1, %2" : "=v"(r.u[1]) : "v"(a.z), "v"(a.w));
  asm("v_cvt_pk_bf16_f32 %0, %1, %2" : "=v"(r.u[2]) : "v"(b.x), "v"(b.y));
  asm("v_cvt_pk_bf16_f32 %0, %1, %2" : "=v"(r.u[3]) : "v"(b.z), "v"(b.w));
  return r.v;
}

// ------- W' in k-chunk-major bf16 layout + STG regularizer accumulation ----
__global__ void k_prep(const float* __restrict__ Wx, const float* __restrict__ Wy,
                       const float* __restrict__ mux, const float* __restrict__ muy,
                       unsigned short* __restrict__ WTx, unsigned short* __restrict__ WTy,
                       float* __restrict__ scal){
  int v = blockIdx.y;
  const float* W  = v ? Wy  : Wx;
  const float* mu = v ? muy : mux;
  unsigned short* WT = v ? WTy : WTx;
  int j = threadIdx.x;
  if (j < 4){   // reg contribution: 0.1 * Phi(mu*sqrt2) / 1024 per element
    float ph = 0.5f * (1.f + erff(mu[blockIdx.x * 4 + j] * 1.41421356237f));
    atomicAdd(scal + 2 + v, 9.765625e-5f * ph);
  }
  #pragma unroll
  for (int r = 0; r < 4; ++r){
    int k = blockIdx.x * 4 + r;
    float g = fminf(fmaxf(mu[k] + 0.5f, 0.f), 1.f);
    WT[(size_t)(k >> 3) * 2048 + j * 8 + (k & 7)] = f2bf(g * W[(size_t)k * DD + j]);
  }
}

// ---------------- big GEMM: Xh = X @ W'  -> bf16 (unchanged from R5) -------
__global__ __launch_bounds__(256, 4) void k_gemm5(
    const float* __restrict__ X, const float* __restrict__ Y,
    const unsigned short* __restrict__ WTx, const unsigned short* __restrict__ WTy,
    unsigned short* __restrict__ Xhb, unsigned short* __restrict__ Yhb){
  const float* A = blockIdx.z ? Y : X;
  const unsigned short* WT = blockIdx.z ? WTy : WTx;
  unsigned short* Out = blockIdx.z ? Yhb : Xhb;

  __shared__ unsigned short As[64][40];
  __shared__ unsigned short Bs[2][4][256][8];

  int tid = threadIdx.x, lane = tid & 63, wid = tid >> 6;
  int wr = wid >> 1, wc = wid & 1;
  int row0 = blockIdx.x * 64;

  f32x4 acc[2][8] = {};

  int s_row = tid >> 2, s_kq = tid & 3;
  const float* ap = A + (size_t)(row0 + s_row) * DXF + s_kq * 8;

  auto stageB = [&](int buf, int ks){
    #pragma unroll
    for (int i = 0; i < 4; ++i)
      gld_lds16(WT + (size_t)(ks * 4 + i) * 2048 + (wid * 64 + lane) * 8,
                &Bs[buf][i][wid * 64][0]);
  };

  float4 a0, a1, n0, n1;
  stageB(0, 0);
  asm volatile("" ::: "memory");
  a0 = *(const float4*)(ap);
  a1 = *(const float4*)(ap + 4);

  for (int ks = 0; ks < 32; ++ks){
    asm volatile("s_waitcnt vmcnt(2)" ::: "memory");
    __builtin_amdgcn_s_barrier();
    if (ks + 1 < 32){
      stageB((ks + 1) & 1, ks + 1);
      asm volatile("" ::: "memory");
      n0 = *(const float4*)(ap + (ks + 1) * 32);
      n1 = *(const float4*)(ap + (ks + 1) * 32 + 4);
      asm volatile("s_waitcnt vmcnt(6)" ::: "memory");
    } else {
      asm volatile("s_waitcnt vmcnt(0)" ::: "memory");
    }
    *(bf16x8*)&As[s_row][s_kq * 8] = pack8(a0, a1);
    asm volatile("s_waitcnt lgkmcnt(0)" ::: "memory");
    __builtin_amdgcn_s_barrier();

    int bb = ks & 1;
    bf16x8 af0 = *(const bf16x8*)&As[wr * 32 + (lane & 15)][(lane >> 4) * 8];
    bf16x8 af1 = *(const bf16x8*)&As[wr * 32 + 16 + (lane & 15)][(lane >> 4) * 8];
    #pragma unroll
    for (int ni = 0; ni < 8; ++ni){
      bf16x8 bf = *(const bf16x8*)&Bs[bb][lane >> 4][wc * 128 + ni * 16 + (lane & 15)][0];
      acc[0][ni] = mfma16(af0, bf, acc[0][ni]);
      acc[1][ni] = mfma16(af1, bf, acc[1][ni]);
    }
    a0 = n0; a1 = n1;
  }

  __syncthreads();
  unsigned short* tl = &Bs[0][0][0][0];
  #pragma unroll
  for (int p = 0; p < 2; ++p){
    if (wr == p){
      #pragma unroll
      for (int mi = 0; mi < 2; ++mi)
        #pragma unroll
        for (int ni = 0; ni < 8; ++ni)
          #pragma unroll
          for (int rr = 0; rr < 4; ++rr){
            int r = mi * 16 + (lane >> 4) * 4 + rr;
            int c = wc * 128 + ni * 16 + (lane & 15);
            tl[r * 256 + c] = f2bf(acc[mi][ni][rr]);
          }
    }
    __syncthreads();
    unsigned short* ob = Out + (size_t)(row0 + p * 32) * DD;
    #pragma unroll
    for (int r = 0; r < 4; ++r){
      int off = r * 2048 + tid * 8;
      *(ushort8_t*)(ob + off) = *(const ushort8_t*)(tl + off);
    }
    if (p == 0) __syncthreads();
  }
}

// ---------------- Gram kernel: split-K partials (unchanged) ----------------
__global__ __launch_bounds__(512) void k_gram(
    const unsigned short* __restrict__ Xhb, const unsigned short* __restrict__ Yhb,
    float* __restrict__ part, float* __restrict__ sx, float* __restrict__ sy, int P){
  int type = blockIdx.z;
  int p = blockIdx.x;
  int chunk = N_S / P;
  int r0 = p * chunk;
  const unsigned short* Asrc = (type == 0) ? Xhb : Yhb;
  const unsigned short* Bsrc = (type == 1) ? Yhb : Xhb;
  bool dualB = (type == 2);

  __shared__ unsigned short At[256][40];
  __shared__ unsigned short Bt[256][40];

  int tid = threadIdx.x;
  int lane = tid & 63, wid = tid >> 6;
  int wr = wid >> 1, wc = wid & 1;

  f32x4 acc[4][8] = {};
  float cs0 = 0.f, cs1 = 0.f;

  int cp  = tid & 127;
  int kb0 = tid >> 7;

  unsigned ua[2][4], ub[2][4];

  auto loadT = [&](int ks){
    int base = r0 + ks * 32;
    #pragma unroll
    for (int r = 0; r < 2; ++r){
      int kb = kb0 + r * 4;
      #pragma unroll
      for (int kr = 0; kr < 4; ++kr){
        ua[r][kr] = *(const unsigned*)(Asrc + (size_t)(base + kb * 4 + kr) * DD + cp * 2);
        if (dualB)
          ub[r][kr] = *(const unsigned*)(Bsrc + (size_t)(base + kb * 4 + kr) * DD + cp * 2);
      }
    }
  };
  auto storeT = [&](){
    #pragma unroll
    for (int r = 0; r < 2; ++r){
      int kb = kb0 + r * 4;
      ushort4_t lo = { (unsigned short)ua[r][0], (unsigned short)ua[r][1],
                       (unsigned short)ua[r][2], (unsigned short)ua[r][3] };
      ushort4_t hi = { (unsigned short)(ua[r][0] >> 16), (unsigned short)(ua[r][1] >> 16),
                       (unsigned short)(ua[r][2] >> 16), (unsigned short)(ua[r][3] >> 16) };
      *(ushort4_t*)&At[cp * 2][kb * 4]     = lo;
      *(ushort4_t*)&At[cp * 2 + 1][kb * 4] = hi;
      if (type < 2){
        #pragma unroll
        for (int kr = 0; kr < 4; ++kr){
          cs0 += bf2f((unsigned short)ua[r][kr]);
          cs1 += bf2f((unsigned short)(ua[r][kr] >> 16));
        }
      }
      if (dualB){
        ushort4_t lob = { (unsigned short)ub[r][0], (unsigned short)ub[r][1],
                          (unsigned short)ub[r][2], (unsigned short)ub[r][3] };
        ushort4_t hib = { (unsigned short)(ub[r][0] >> 16), (unsigned short)(ub[r][1] >> 16),
                          (unsigned short)(ub[r][2] >> 16), (unsigned short)(ub[r][3] >> 16) };
        *(ushort4_t*)&Bt[cp * 2][kb * 4]     = lob;
        *(ushort4_t*)&Bt[cp * 2 + 1][kb * 4] = hib;
      }
    }
  };

  unsigned short (*Btp)[40] = dualB ? Bt : At;

  int KS = chunk / 32;
  loadT(0);
  for (int ks = 0; ks < KS; ++ks){
    __syncthreads();
    storeT();
    __syncthreads();
    if (ks + 1 < KS) loadT(ks + 1);
    bf16x8 af[4], bfv[8];
    #pragma unroll
    for (int mi = 0; mi < 4; ++mi)
      af[mi] = *(const bf16x8*)&At[wr * 64 + mi * 16 + (lane & 15)][(lane >> 4) * 8];
    #pragma unroll
    for (int ni = 0; ni < 8; ++ni)
      bfv[ni] = *(const bf16x8*)&Btp[wc * 128 + ni * 16 + (lane & 15)][(lane >> 4) * 8];
    #pragma unroll
    for (int mi = 0; mi < 4; ++mi)
      #pragma unroll
      for (int ni = 0; ni < 8; ++ni)
        acc[mi][ni] = mfma16(af[mi], bfv[ni], acc[mi][ni]);
  }

  float* dst = part + ((size_t)p * 3 + type) * 65536;
  #pragma unroll
  for (int mi = 0; mi < 4; ++mi)
    #pragma unroll
    for (int ni = 0; ni < 8; ++ni)
      #pragma unroll
      for (int rr = 0; rr < 4; ++rr){
        int grow = wr * 64 + mi * 16 + (lane >> 4) * 4 + rr;
        int gcol = wc * 128 + ni * 16 + (lane & 15);
        dst[(size_t)grow * 256 + gcol] = acc[mi][ni][rr];
      }

  if (type < 2){
    __syncthreads();
    float* red = (float*)&At[0][0];
    red[kb0 * 256 + cp * 2]     = cs0;
    red[kb0 * 256 + cp * 2 + 1] = cs1;
    __syncthreads();
    if (tid < 256){
      float s = red[tid] + red[256 + tid] + red[512 + tid] + red[768 + tid];
      atomicAdd((type == 0 ? sx : sy) + tid, s);
    }
  }
}

// -------- reduce partials -> A,B (fp32+bf16), C bf16(+T), inf-norms --------
__global__ void k_reduce(const float* __restrict__ part, const float* __restrict__ sx,
                         const float* __restrict__ sy, float* __restrict__ Am,
                         float* __restrict__ Bm,
                         unsigned short* __restrict__ Abf, unsigned short* __restrict__ Bbf,
                         unsigned short* __restrict__ Cbf, unsigned short* __restrict__ CbfT,
                         float* __restrict__ scal, int P){
  __shared__ float r2[256];
  int i = blockIdx.x, j = threadIdx.x;
  size_t idx = (size_t)i * 256 + j;
  float gxx = 0.f, gyy = 0.f, gyx = 0.f;
  for (int p = 0; p < P; ++p){
    const float* b = part + (size_t)p * 3 * 65536;
    gxx += b[idx];
    gyy += b[65536 + idx];
    gyx += b[131072 + idx];
  }
  float invn1 = 1.f / NM1;
  float invn  = 1.f / (float)N_S;
  float sxi = sx[i], sxj = sx[j], syi = sy[i], syj = sy[j];
  float diag = (i == j) ? 1.f : 0.f;
  float am = (gyy - syi * syj * invn) * invn1 + diag * (2.f * EPSR);
  float bm = (gxx - sxi * sxj * invn) * invn1 + diag * EPSR;
  float cv = (gyx - syi * sxj * invn) * invn1;
  Am[idx] = am;  Bm[idx] = bm;
  Abf[idx] = f2bf(am);
  Bbf[idx] = f2bf(bm);
  Cbf[idx] = f2bf(cv);
  CbfT[(size_t)j * 256 + i] = f2bf(cv);
  // row inf-norm sums -> scal[5] (A), scal[6] (B) via atomicMax
  r2[j] = fabsf(am);
  __syncthreads();
  for (int s = 128; s > 0; s >>= 1){ if (j < s) r2[j] += r2[j + s]; __syncthreads(); }
  if (j == 0) atomicMax((unsigned*)scal + 5, __float_as_uint(r2[0]));
  __syncthreads();
  r2[j] = fabsf(bm);
  __syncthreads();
  for (int s = 128; s > 0; s >>= 1){ if (j < s) r2[j] += r2[j + s]; __syncthreads(); }
  if (j == 0) atomicMax((unsigned*)scal + 6, __float_as_uint(r2[0]));
}

// -------- X1 = 2aI - a^2 M  (NS step 1 closed form), a = 1.9/||M||inf ------
__global__ void k_x1(const float* __restrict__ Am, const float* __restrict__ Bm,
                     unsigned short* __restrict__ X0, const float* __restrict__ scal){
  int m = blockIdx.y;
  const unsigned* su = (const unsigned*)scal;
  float al = 1.9f / __uint_as_float(su[5 + m]);
  const float* M = m ? Bm : Am;
  int e = blockIdx.x * 512 + threadIdx.x;
  float v = -al * al * M[e];
  if ((e >> 8) == (e & 255)) v += 2.f * al;
  X0[m * 65536 + e] = f2bf(v);
}

// -------- one NS iteration, col-block local: X'_j = 2X_j - X*(M*X_j) -------
// grid (8 col-blocks of 32, 2 matrices), 512 thr (8 waves), mfma32.
// X symmetric -> all B-operands read as rows; LDS rotation swizzle.
__global__ __launch_bounds__(512) void k_it(
    const unsigned short* __restrict__ Abf, const unsigned short* __restrict__ Bbf,
    const unsigned short* __restrict__ Xc, unsigned short* __restrict__ Xn){
  int m = blockIdx.y, j = blockIdx.x;
  const unsigned short* M  = m ? Bbf : Abf;
  const unsigned short* Xm = Xc + m * 65536;
  unsigned short*       Xo = Xn + m * 65536;

  __shared__ unsigned short XJ[32 * 256];   // rot-swz [c_loc][k]: X rows j*32..
  __shared__ unsigned short TT[32 * 256];   // rot-swz [c_loc][k]: T^T

  int tid = threadIdx.x, lane = tid & 63, w = tid >> 6;
  int r31 = lane & 31, kh = lane >> 5;

  // stage XJ (inverse-rotated source, linear dest)
  #pragma unroll
  for (int i = 0; i < 2; ++i){
    int rl = w * 4 + i * 2 + kh;
    int cg = ((lane & 31) - rl) & 31;
    gld_lds16(Xm + (size_t)(j * 32 + rl) * 256 + cg * 8, &XJ[(w * 4 + i * 2) * 256]);
  }
  asm volatile("s_waitcnt vmcnt(0)" ::: "memory");
  __builtin_amdgcn_s_barrier();

  // phase 1: T rows [w*32..) x 32 cols = M_rows x XJ
  f32x16 acc = {};
  const unsigned short* arow = M + (size_t)(w * 32 + r31) * 256 + kh * 8;
  #pragma unroll
  for (int ks = 0; ks < 16; ++ks){
    bf16x8 af = *(const bf16x8*)(arow + ks * 16);
    int ch = ((ks * 2 + kh) + r31) & 31;
    bf16x8 bf = *(const bf16x8*)&XJ[r31 * 256 + ch * 8];
    acc = mfma32(af, bf, acc);
  }
  // scatter T^T (conflict-free by rotation)
  #pragma unroll
  for (int reg = 0; reg < 16; ++reg){
    int kk = w * 32 + (reg & 3) + ((reg >> 2) << 3) + (kh << 2);
    int ch = ((kk >> 3) + r31) & 31;
    TT[r31 * 256 + ch * 8 + (kk & 7)] = f2bf(acc[reg]);
  }
  __syncthreads();

  // phase 2: X'_rows = 2X - X_rows * T  (B-op = TT rows)
  f32x16 acc2 = {};
  const unsigned short* xrow = Xm + (size_t)(w * 32 + r31) * 256 + kh * 8;
  #pragma unroll
  for (int ks = 0; ks < 16; ++ks){
    bf16x8 af = *(const bf16x8*)(xrow + ks * 16);
    int ch = ((ks * 2 + kh) + r31) & 31;
    bf16x8 bf = *(const bf16x8*)&TT[r31 * 256 + ch * 8];
    acc2 = mfma32(af, bf, acc2);
  }
  #pragma unroll
  for (int reg = 0; reg < 16; ++reg){
    int row = w * 32 + (reg & 3) + ((reg >> 2) << 3) + (kh << 2);
    int ch = ((row >> 3) + r31) & 31;
    float xv = bf2f(XJ[r31 * 256 + ch * 8 + (row & 7)]);   // X[row][col] via symmetry
    Xo[(size_t)row * 256 + j * 32 + r31] = f2bf(2.f * xv - acc2[reg]);
  }
}

// -------- U = XA*C (mat0) ; W = C*XB = V^T (mat1) ; f32 outputs ------------
__global__ __launch_bounds__(512) void k_uv(
    const unsigned short* __restrict__ Xf,
    const unsigned short* __restrict__ Cbf, const unsigned short* __restrict__ CbfT,
    float* __restrict__ U, float* __restrict__ W){
  int m = blockIdx.y, j = blockIdx.x;
  __shared__ unsigned short BJ[32 * 256];
  int tid = threadIdx.x, lane = tid & 63, w = tid >> 6;
  int r31 = lane & 31, kh = lane >> 5;
  const unsigned short* Brows = m ? (Xf + 65536) : CbfT;
  const unsigned short* Arows = m ? Cbf : Xf;
  float* D = m ? W : U;

  #pragma unroll
  for (int i = 0; i < 2; ++i){
    int rl = w * 4 + i * 2 + kh;
    int cg = ((lane & 31) - rl) & 31;
    gld_lds16(Brows + (size_t)(j * 32 + rl) * 256 + cg * 8, &BJ[(w * 4 + i * 2) * 256]);
  }
  asm volatile("s_waitcnt vmcnt(0)" ::: "memory");
  __builtin_amdgcn_s_barrier();

  f32x16 acc = {};
  const unsigned short* ar = Arows + (size_t)(w * 32 + r31) * 256 + kh * 8;
  #pragma unroll
  for (int ks = 0; ks < 16; ++ks){
    bf16x8 af = *(const bf16x8*)(ar + ks * 16);
    int ch = ((ks * 2 + kh) + r31) & 31;
    bf16x8 bf = *(const bf16x8*)&BJ[r31 * 256 + ch * 8];
    acc = mfma32(af, bf, acc);
  }
  #pragma unroll
  for (int reg = 0; reg < 16; ++reg){
    int row = w * 32 + (reg & 3) + ((reg >> 2) << 3) + (kh << 2);
    D[(size_t)row * 256 + j * 32 + r31] = acc[reg];
  }
}

// -------- final: loss = -sum(U*W)/256 + regx + regy ------------------------
__global__ __launch_bounds__(1024) void k_fin(const float* __restrict__ U,
                                              const float* __restrict__ W,
                                              const float* __restrict__ scal,
                                              float* __restrict__ out){
  __shared__ float red[1024];
  int tid = threadIdx.x;
  float t = 0.f;
  #pragma unroll
  for (int r = 0; r < 16; ++r){
    int i = r * 4096 + tid * 4;
    float4 u = *(const float4*)(U + i);
    float4 w = *(const float4*)(W + i);
    t += u.x * w.x + u.y * w.y + u.z * w.z + u.w * w.w;
  }
  red[tid] = t; __syncthreads();
  for (int s = 512; s > 0; s >>= 1){ if (tid < s) red[tid] += red[tid + s]; __syncthreads(); }
  if (tid == 0) out[0] = -red[0] / 256.f + scal[2] + scal[3];
}

extern "C" void kernel_launch(void* const* d_in, const int* in_sizes, int n_in,
                              void* d_out, int out_size, void* d_ws, size_t ws_size,
                              hipStream_t stream){
  (void)in_sizes; (void)n_in; (void)out_size;
  const float* X   = (const float*)d_in[0];
  const float* Y   = (const float*)d_in[1];
  const float* mux = (const float*)d_in[2];
  const float* muy = (const float*)d_in[3];
  const float* Wx  = (const float*)d_in[4];
  const float* Wy  = (const float*)d_in[6];
  float* out = (float*)d_out;
  char* ws = (char*)d_ws;

  const size_t MB = 1ull << 20;
  const size_t KB = 1024;
  size_t oXHB = 0;
  size_t oYHB = 32 * MB;
  size_t oWTX = 64 * MB;
  size_t oWTY = oWTX + 512 * KB;
  size_t oSX  = oWTY + 512 * KB;
  size_t oSY  = oSX + 4 * KB;
  size_t oSC  = oSY + 4 * KB;
  size_t oA   = oSC + 4 * KB;
  size_t oB   = oA   + 256 * KB;
  size_t oABF = oB   + 256 * KB;
  size_t oBBF = oABF + 128 * KB;
  size_t oCBF = oBBF + 128 * KB;
  size_t oCBT = oCBF + 128 * KB;
  size_t oX0  = oCBT + 128 * KB;
  size_t oX1  = oX0  + 256 * KB;
  size_t oTB  = oX1  + 256 * KB;
  size_t oU   = oTB  + 256 * KB;
  size_t oV   = oU   + 256 * KB;
  size_t oPart = 68 * MB;

  size_t per = 3ull * 65536 * 4;
  int P = 128;
  while (P > 8 && oPart + (size_t)P * per > ws_size) P >>= 1;

  unsigned short* Xhb = (unsigned short*)(ws + oXHB);
  unsigned short* Yhb = (unsigned short*)(ws + oYHB);
  unsigned short* WTx = (unsigned short*)(ws + oWTX);
  unsigned short* WTy = (unsigned short*)(ws + oWTY);
  float* sx   = (float*)(ws + oSX);
  float* sy   = (float*)(ws + oSY);
  float* scal = (float*)(ws + oSC);
  float* Am   = (float*)(ws + oA);
  float* Bm   = (float*)(ws + oB);
  unsigned short* Abf  = (unsigned short*)(ws + oABF);
  unsigned short* Bbf  = (unsigned short*)(ws + oBBF);
  unsigned short* Cbf  = (unsigned short*)(ws + oCBF);
  unsigned short* CbfT = (unsigned short*)(ws + oCBT);
  unsigned short* X0   = (unsigned short*)(ws + oX0);
  unsigned short* X1   = (unsigned short*)(ws + oX1);
  float* U    = (float*)(ws + oU);
  float* V    = (float*)(ws + oV);
  float* part = (float*)(ws + oPart);

  // zero sx, sy, scal (12KB contiguous)
  hipMemsetAsync(ws + oSX, 0, 12 * KB, stream);

  k_prep<<<dim3(256, 2), 256, 0, stream>>>(Wx, Wy, mux, muy, WTx, WTy, scal);
  k_gemm5<<<dim3(1024, 1, 2), 256, 0, stream>>>(X, Y, WTx, WTy, Xhb, Yhb);
  k_gram<<<dim3(P, 1, 3), 512, 0, stream>>>(Xhb, Yhb, part, sx, sy, P);
  k_reduce<<<256, 256, 0, stream>>>(part, sx, sy, Am, Bm, Abf, Bbf, Cbf, CbfT, scal, P);

  k_x1<<<dim3(128, 2), 512, 0, stream>>>(Am, Bm, X0, scal);
  k_it<<<dim3(8, 2), 512, 0, stream>>>(Abf, Bbf, X0, X1);
  k_it<<<dim3(8, 2), 512, 0, stream>>>(Abf, Bbf, X1, X0);
  k_it<<<dim3(8, 2), 512, 0, stream>>>(Abf, Bbf, X0, X1);
  k_it<<<dim3(8, 2), 512, 0, stream>>>(Abf, Bbf, X1, X0);
  k_it<<<dim3(8, 2), 512, 0, stream>>>(Abf, Bbf, X0, X1);   // final in X1
  k_uv<<<dim3(8, 2), 512, 0, stream>>>(X1, Cbf, CbfT, U, V);
  k_fin<<<1, 1024, 0, stream>>>(U, V, scal, out);
}

// Round 7
// 341.831 us; speedup vs baseline: 1.6055x; 1.0106x over previous
//
#include <hip/hip_runtime.h>

#define N_S   65536
#define DXF   1024
#define DD    256
#define NM1   65535.0f
#define EPSR  0.001f

typedef __attribute__((ext_vector_type(4)))  float          f32x4;
typedef __attribute__((ext_vector_type(16))) float          f32x16;
typedef __attribute__((ext_vector_type(8)))  short          bf16x8;
typedef __attribute__((ext_vector_type(4)))  unsigned short ushort4_t;
typedef __attribute__((ext_vector_type(8)))  unsigned short ushort8_t;

__device__ __forceinline__ unsigned short f2bf(float f){
  unsigned u = __float_as_uint(f);
  u += 0x7fffu + ((u >> 16) & 1u);   // RNE
  return (unsigned short)(u >> 16);
}
__device__ __forceinline__ float bf2f(unsigned short h){
  return __uint_as_float(((unsigned)h) << 16);
}
__device__ __forceinline__ f32x4 mfma16(bf16x8 a, bf16x8 b, f32x4 c){
  return __builtin_amdgcn_mfma_f32_16x16x32_bf16(a, b, c, 0, 0, 0);
}
__device__ __forceinline__ f32x16 mfma32(bf16x8 a, bf16x8 b, f32x16 c){
  return __builtin_amdgcn_mfma_f32_32x32x16_bf16(a, b, c, 0, 0, 0);
}
__device__ __forceinline__ void gld_lds16(const void* g, void* l){
  __builtin_amdgcn_global_load_lds(
      (const __attribute__((address_space(1))) unsigned int*)g,
      (__attribute__((address_space(3))) unsigned int*)l, 16, 0, 0);
}
__device__ __forceinline__ bf16x8 pack8(float4 a, float4 b){
  union { unsigned u[4]; bf16x8 v; } r;
  asm("v_cvt_pk_bf16_f32 %0, %1, %2" : "=v"(r.u[0]) : "v"(a.x), "v"(a.y));
  asm("v_cvt_pk_bf16_f32 %0, %1, %2" : "=v"(r.u[1]) : "v"(a.z), "v"(a.w));
  asm("v_cvt_pk_bf16_f32 %0, %1, %2" : "=v"(r.u[2]) : "v"(b.x), "v"(b.y));
  asm("v_cvt_pk_bf16_f32 %0, %1, %2" : "=v"(r.u[3]) : "v"(b.z), "v"(b.w));
  return r.v;
}

// ------- W' in k-chunk-major bf16 layout + STG regularizer accumulation ----
__global__ void k_prep(const float* __restrict__ Wx, const float* __restrict__ Wy,
                       const float* __restrict__ mux, const float* __restrict__ muy,
                       unsigned short* __restrict__ WTx, unsigned short* __restrict__ WTy,
                       float* __restrict__ scal){
  int v = blockIdx.y;
  const float* W  = v ? Wy  : Wx;
  const float* mu = v ? muy : mux;
  unsigned short* WT = v ? WTy : WTx;
  int j = threadIdx.x;
  if (j < 4){   // reg contribution: 0.1 * Phi(mu*sqrt2) / 1024 per element
    float ph = 0.5f * (1.f + erff(mu[blockIdx.x * 4 + j] * 1.41421356237f));
    atomicAdd(scal + 2 + v, 9.765625e-5f * ph);
  }
  #pragma unroll
  for (int r = 0; r < 4; ++r){
    int k = blockIdx.x * 4 + r;
    float g = fminf(fmaxf(mu[k] + 0.5f, 0.f), 1.f);
    WT[(size_t)(k >> 3) * 2048 + j * 8 + (k & 7)] = f2bf(g * W[(size_t)k * DD + j]);
  }
}

// ---------------- big GEMM: Xh = X @ W'  -> bf16 ---------------------------
// 256 thr (4 waves), tile 64x256, wave 32x256, 16x16x32 MFMA.
// B: 2-DEEP prefetch, tri-buffered (T3/T4: loads span 2 compute phases so the
// stage stall amortizes). A: 1-deep reg prefetch -> cvt_pk -> LDS.
// LDS 29KB -> 5 blocks/CU (~20 waves) for inter-block bubble filling.
__global__ __launch_bounds__(256, 4) void k_gemm6(
    const float* __restrict__ X, const float* __restrict__ Y,
    const unsigned short* __restrict__ WTx, const unsigned short* __restrict__ WTy,
    unsigned short* __restrict__ Xhb, unsigned short* __restrict__ Yhb){
  const float* A = blockIdx.z ? Y : X;
  const unsigned short* WT = blockIdx.z ? WTy : WTx;
  unsigned short* Out = blockIdx.z ? Yhb : Xhb;

  __shared__ unsigned short As[64][40];          // 5KB
  __shared__ unsigned short Bs[3][4][256][8];    // 24KB tri-buffer

  int tid = threadIdx.x, lane = tid & 63, wid = tid >> 6;
  int wr = wid >> 1, wc = wid & 1;
  int row0 = blockIdx.x * 64;

  f32x4 acc[2][8] = {};

  int s_row = tid >> 2, s_kq = tid & 3;
  const float* ap = A + (size_t)(row0 + s_row) * DXF + s_kq * 8;

  auto stageB = [&](int buf, int ks){
    #pragma unroll
    for (int i = 0; i < 4; ++i)
      gld_lds16(WT + (size_t)(ks * 4 + i) * 2048 + (wid * 64 + lane) * 8,
                &Bs[buf][i][wid * 64][0]);
  };

  float4 a0, a1, n0, n1;
  // prologue: B(0), B(1) staged; A(0) in regs.  outstanding: 4+4+2
  stageB(0, 0);
  stageB(1, 1);
  asm volatile("" ::: "memory");
  a0 = *(const float4*)(ap);
  a1 = *(const float4*)(ap + 4);

  for (int ks = 0; ks < 32; ++ks){
    // wait B(ks); keep B(ks+1) + A(ks) in flight
    if (ks < 31) asm volatile("s_waitcnt vmcnt(6)" ::: "memory");
    else         asm volatile("s_waitcnt vmcnt(2)" ::: "memory");
    __builtin_amdgcn_s_barrier();
    if (ks + 2 < 32) stageB((ks + 2) % 3, ks + 2);
    if (ks + 1 < 32){
      asm volatile("" ::: "memory");
      n0 = *(const float4*)(ap + (ks + 1) * 32);
      n1 = *(const float4*)(ap + (ks + 1) * 32 + 4);
    }
    // wait A(ks); keep B(ks+1), B(ks+2), A(ks+1) in flight
    if (ks < 30)      asm volatile("s_waitcnt vmcnt(6)" ::: "memory");
    else if (ks < 31) asm volatile("s_waitcnt vmcnt(2)" ::: "memory");
    else              asm volatile("s_waitcnt vmcnt(0)" ::: "memory");
    *(bf16x8*)&As[s_row][s_kq * 8] = pack8(a0, a1);
    asm volatile("s_waitcnt lgkmcnt(0)" ::: "memory");
    __builtin_amdgcn_s_barrier();

    int bb = ks % 3;
    bf16x8 af0 = *(const bf16x8*)&As[wr * 32 + (lane & 15)][(lane >> 4) * 8];
    bf16x8 af1 = *(const bf16x8*)&As[wr * 32 + 16 + (lane & 15)][(lane >> 4) * 8];
    #pragma unroll
    for (int ni = 0; ni < 8; ++ni){
      bf16x8 bf = *(const bf16x8*)&Bs[bb][lane >> 4][wc * 128 + ni * 16 + (lane & 15)][0];
      acc[0][ni] = mfma16(af0, bf, acc[0][ni]);
      acc[1][ni] = mfma16(af1, bf, acc[1][ni]);
    }
    a0 = n0; a1 = n1;
  }

  // epilogue: 2-pass LDS transpose (16KB of Bs) -> coalesced bf16 stores
  __syncthreads();
  unsigned short* tl = &Bs[0][0][0][0];
  #pragma unroll
  for (int p = 0; p < 2; ++p){
    if (wr == p){
      #pragma unroll
      for (int mi = 0; mi < 2; ++mi)
        #pragma unroll
        for (int ni = 0; ni < 8; ++ni)
          #pragma unroll
          for (int rr = 0; rr < 4; ++rr){
            int r = mi * 16 + (lane >> 4) * 4 + rr;
            int c = wc * 128 + ni * 16 + (lane & 15);
            tl[r * 256 + c] = f2bf(acc[mi][ni][rr]);
          }
    }
    __syncthreads();
    unsigned short* ob = Out + (size_t)(row0 + p * 32) * DD;
    #pragma unroll
    for (int r = 0; r < 4; ++r){
      int off = r * 2048 + tid * 8;
      *(ushort8_t*)(ob + off) = *(const ushort8_t*)(tl + off);
    }
    if (p == 0) __syncthreads();
  }
}

// ---------------- Gram kernel: split-K partials (unchanged) ----------------
__global__ __launch_bounds__(512) void k_gram(
    const unsigned short* __restrict__ Xhb, const unsigned short* __restrict__ Yhb,
    float* __restrict__ part, float* __restrict__ sx, float* __restrict__ sy, int P){
  int type = blockIdx.z;
  int p = blockIdx.x;
  int chunk = N_S / P;
  int r0 = p * chunk;
  const unsigned short* Asrc = (type == 0) ? Xhb : Yhb;
  const unsigned short* Bsrc = (type == 1) ? Yhb : Xhb;
  bool dualB = (type == 2);

  __shared__ unsigned short At[256][40];
  __shared__ unsigned short Bt[256][40];

  int tid = threadIdx.x;
  int lane = tid & 63, wid = tid >> 6;
  int wr = wid >> 1, wc = wid & 1;

  f32x4 acc[4][8] = {};
  float cs0 = 0.f, cs1 = 0.f;

  int cp  = tid & 127;
  int kb0 = tid >> 7;

  unsigned ua[2][4], ub[2][4];

  auto loadT = [&](int ks){
    int base = r0 + ks * 32;
    #pragma unroll
    for (int r = 0; r < 2; ++r){
      int kb = kb0 + r * 4;
      #pragma unroll
      for (int kr = 0; kr < 4; ++kr){
        ua[r][kr] = *(const unsigned*)(Asrc + (size_t)(base + kb * 4 + kr) * DD + cp * 2);
        if (dualB)
          ub[r][kr] = *(const unsigned*)(Bsrc + (size_t)(base + kb * 4 + kr) * DD + cp * 2);
      }
    }
  };
  auto storeT = [&](){
    #pragma unroll
    for (int r = 0; r < 2; ++r){
      int kb = kb0 + r * 4;
      ushort4_t lo = { (unsigned short)ua[r][0], (unsigned short)ua[r][1],
                       (unsigned short)ua[r][2], (unsigned short)ua[r][3] };
      ushort4_t hi = { (unsigned short)(ua[r][0] >> 16), (unsigned short)(ua[r][1] >> 16),
                       (unsigned short)(ua[r][2] >> 16), (unsigned short)(ua[r][3] >> 16) };
      *(ushort4_t*)&At[cp * 2][kb * 4]     = lo;
      *(ushort4_t*)&At[cp * 2 + 1][kb * 4] = hi;
      if (type < 2){
        #pragma unroll
        for (int kr = 0; kr < 4; ++kr){
          cs0 += bf2f((unsigned short)ua[r][kr]);
          cs1 += bf2f((unsigned short)(ua[r][kr] >> 16));
        }
      }
      if (dualB){
        ushort4_t lob = { (unsigned short)ub[r][0], (unsigned short)ub[r][1],
                          (unsigned short)ub[r][2], (unsigned short)ub[r][3] };
        ushort4_t hib = { (unsigned short)(ub[r][0] >> 16), (unsigned short)(ub[r][1] >> 16),
                          (unsigned short)(ub[r][2] >> 16), (unsigned short)(ub[r][3] >> 16) };
        *(ushort4_t*)&Bt[cp * 2][kb * 4]     = lob;
        *(ushort4_t*)&Bt[cp * 2 + 1][kb * 4] = hib;
      }
    }
  };

  unsigned short (*Btp)[40] = dualB ? Bt : At;

  int KS = chunk / 32;
  loadT(0);
  for (int ks = 0; ks < KS; ++ks){
    __syncthreads();
    storeT();
    __syncthreads();
    if (ks + 1 < KS) loadT(ks + 1);
    bf16x8 af[4], bfv[8];
    #pragma unroll
    for (int mi = 0; mi < 4; ++mi)
      af[mi] = *(const bf16x8*)&At[wr * 64 + mi * 16 + (lane & 15)][(lane >> 4) * 8];
    #pragma unroll
    for (int ni = 0; ni < 8; ++ni)
      bfv[ni] = *(const bf16x8*)&Btp[wc * 128 + ni * 16 + (lane & 15)][(lane >> 4) * 8];
    #pragma unroll
    for (int mi = 0; mi < 4; ++mi)
      #pragma unroll
      for (int ni = 0; ni < 8; ++ni)
        acc[mi][ni] = mfma16(af[mi], bfv[ni], acc[mi][ni]);
  }

  float* dst = part + ((size_t)p * 3 + type) * 65536;
  #pragma unroll
  for (int mi = 0; mi < 4; ++mi)
    #pragma unroll
    for (int ni = 0; ni < 8; ++ni)
      #pragma unroll
      for (int rr = 0; rr < 4; ++rr){
        int grow = wr * 64 + mi * 16 + (lane >> 4) * 4 + rr;
        int gcol = wc * 128 + ni * 16 + (lane & 15);
        dst[(size_t)grow * 256 + gcol] = acc[mi][ni][rr];
      }

  if (type < 2){
    __syncthreads();
    float* red = (float*)&At[0][0];
    red[kb0 * 256 + cp * 2]     = cs0;
    red[kb0 * 256 + cp * 2 + 1] = cs1;
    __syncthreads();
    if (tid < 256){
      float s = red[tid] + red[256 + tid] + red[512 + tid] + red[768 + tid];
      atomicAdd((type == 0 ? sx : sy) + tid, s);
    }
  }
}

// -------- reduce partials -> A,B (fp32+bf16), C bf16(+T), inf-norms --------
__global__ void k_reduce(const float* __restrict__ part, const float* __restrict__ sx,
                         const float* __restrict__ sy, float* __restrict__ Am,
                         float* __restrict__ Bm,
                         unsigned short* __restrict__ Abf, unsigned short* __restrict__ Bbf,
                         unsigned short* __restrict__ Cbf, unsigned short* __restrict__ CbfT,
                         float* __restrict__ scal, int P){
  __shared__ float r2[256];
  int i = blockIdx.x, j = threadIdx.x;
  size_t idx = (size_t)i * 256 + j;
  float gxx = 0.f, gyy = 0.f, gyx = 0.f;
  for (int p = 0; p < P; ++p){
    const float* b = part + (size_t)p * 3 * 65536;
    gxx += b[idx];
    gyy += b[65536 + idx];
    gyx += b[131072 + idx];
  }
  float invn1 = 1.f / NM1;
  float invn  = 1.f / (float)N_S;
  float sxi = sx[i], sxj = sx[j], syi = sy[i], syj = sy[j];
  float diag = (i == j) ? 1.f : 0.f;
  float am = (gyy - syi * syj * invn) * invn1 + diag * (2.f * EPSR);
  float bm = (gxx - sxi * sxj * invn) * invn1 + diag * EPSR;
  float cv = (gyx - syi * sxj * invn) * invn1;
  Am[idx] = am;  Bm[idx] = bm;
  Abf[idx] = f2bf(am);
  Bbf[idx] = f2bf(bm);
  Cbf[idx] = f2bf(cv);
  CbfT[(size_t)j * 256 + i] = f2bf(cv);
  r2[j] = fabsf(am);
  __syncthreads();
  for (int s = 128; s > 0; s >>= 1){ if (j < s) r2[j] += r2[j + s]; __syncthreads(); }
  if (j == 0) atomicMax((unsigned*)scal + 5, __float_as_uint(r2[0]));
  __syncthreads();
  r2[j] = fabsf(bm);
  __syncthreads();
  for (int s = 128; s > 0; s >>= 1){ if (j < s) r2[j] += r2[j + s]; __syncthreads(); }
  if (j == 0) atomicMax((unsigned*)scal + 6, __float_as_uint(r2[0]));
}

// -------- X1 = 2aI - a^2 M  (NS step 1 closed form), a = 1.9/||M||inf ------
__global__ void k_x1(const float* __restrict__ Am, const float* __restrict__ Bm,
                     unsigned short* __restrict__ X0, const float* __restrict__ scal){
  int m = blockIdx.y;
  const unsigned* su = (const unsigned*)scal;
  float al = 1.9f / __uint_as_float(su[5 + m]);
  const float* M = m ? Bm : Am;
  int e = blockIdx.x * 512 + threadIdx.x;
  float v = -al * al * M[e];
  if ((e >> 8) == (e & 255)) v += 2.f * al;
  X0[m * 65536 + e] = f2bf(v);
}

// -------- one NS iteration, col-block local: X'_j = 2X_j - X*(M*X_j) -------
__global__ __launch_bounds__(512) void k_it(
    const unsigned short* __restrict__ Abf, const unsigned short* __restrict__ Bbf,
    const unsigned short* __restrict__ Xc, unsigned short* __restrict__ Xn){
  int m = blockIdx.y, j = blockIdx.x;
  const unsigned short* M  = m ? Bbf : Abf;
  const unsigned short* Xm = Xc + m * 65536;
  unsigned short*       Xo = Xn + m * 65536;

  __shared__ unsigned short XJ[32 * 256];
  __shared__ unsigned short TT[32 * 256];

  int tid = threadIdx.x, lane = tid & 63, w = tid >> 6;
  int r31 = lane & 31, kh = lane >> 5;

  #pragma unroll
  for (int i = 0; i < 2; ++i){
    int rl = w * 4 + i * 2 + kh;
    int cg = ((lane & 31) - rl) & 31;
    gld_lds16(Xm + (size_t)(j * 32 + rl) * 256 + cg * 8, &XJ[(w * 4 + i * 2) * 256]);
  }
  asm volatile("s_waitcnt vmcnt(0)" ::: "memory");
  __builtin_amdgcn_s_barrier();

  f32x16 acc = {};
  const unsigned short* arow = M + (size_t)(w * 32 + r31) * 256 + kh * 8;
  #pragma unroll
  for (int ks = 0; ks < 16; ++ks){
    bf16x8 af = *(const bf16x8*)(arow + ks * 16);
    int ch = ((ks * 2 + kh) + r31) & 31;
    bf16x8 bf = *(const bf16x8*)&XJ[r31 * 256 + ch * 8];
    acc = mfma32(af, bf, acc);
  }
  #pragma unroll
  for (int reg = 0; reg < 16; ++reg){
    int kk = w * 32 + (reg & 3) + ((reg >> 2) << 3) + (kh << 2);
    int ch = ((kk >> 3) + r31) & 31;
    TT[r31 * 256 + ch * 8 + (kk & 7)] = f2bf(acc[reg]);
  }
  __syncthreads();

  f32x16 acc2 = {};
  const unsigned short* xrow = Xm + (size_t)(w * 32 + r31) * 256 + kh * 8;
  #pragma unroll
  for (int ks = 0; ks < 16; ++ks){
    bf16x8 af = *(const bf16x8*)(xrow + ks * 16);
    int ch = ((ks * 2 + kh) + r31) & 31;
    bf16x8 bf = *(const bf16x8*)&TT[r31 * 256 + ch * 8];
    acc2 = mfma32(af, bf, acc2);
  }
  #pragma unroll
  for (int reg = 0; reg < 16; ++reg){
    int row = w * 32 + (reg & 3) + ((reg >> 2) << 3) + (kh << 2);
    int ch = ((row >> 3) + r31) & 31;
    float xv = bf2f(XJ[r31 * 256 + ch * 8 + (row & 7)]);
    Xo[(size_t)row * 256 + j * 32 + r31] = f2bf(2.f * xv - acc2[reg]);
  }
}

// -------- U = XA*C (mat0) ; W = C*XB = V^T (mat1) ; f32 outputs ------------
__global__ __launch_bounds__(512) void k_uv(
    const unsigned short* __restrict__ Xf,
    const unsigned short* __restrict__ Cbf, const unsigned short* __restrict__ CbfT,
    float* __restrict__ U, float* __restrict__ W){
  int m = blockIdx.y, j = blockIdx.x;
  __shared__ unsigned short BJ[32 * 256];
  int tid = threadIdx.x, lane = tid & 63, w = tid >> 6;
  int r31 = lane & 31, kh = lane >> 5;
  const unsigned short* Brows = m ? (Xf + 65536) : CbfT;
  const unsigned short* Arows = m ? Cbf : Xf;
  float* D = m ? W : U;

  #pragma unroll
  for (int i = 0; i < 2; ++i){
    int rl = w * 4 + i * 2 + kh;
    int cg = ((lane & 31) - rl) & 31;
    gld_lds16(Brows + (size_t)(j * 32 + rl) * 256 + cg * 8, &BJ[(w * 4 + i * 2) * 256]);
  }
  asm volatile("s_waitcnt vmcnt(0)" ::: "memory");
  __builtin_amdgcn_s_barrier();

  f32x16 acc = {};
  const unsigned short* ar = Arows + (size_t)(w * 32 + r31) * 256 + kh * 8;
  #pragma unroll
  for (int ks = 0; ks < 16; ++ks){
    bf16x8 af = *(const bf16x8*)(ar + ks * 16);
    int ch = ((ks * 2 + kh) + r31) & 31;
    bf16x8 bf = *(const bf16x8*)&BJ[r31 * 256 + ch * 8];
    acc = mfma32(af, bf, acc);
  }
  #pragma unroll
  for (int reg = 0; reg < 16; ++reg){
    int row = w * 32 + (reg & 3) + ((reg >> 2) << 3) + (kh << 2);
    D[(size_t)row * 256 + j * 32 + r31] = acc[reg];
  }
}

// -------- final: loss = -sum(U*W)/256 + regx + regy ------------------------
__global__ __launch_bounds__(1024) void k_fin(const float* __restrict__ U,
                                              const float* __restrict__ W,
                                              const float* __restrict__ scal,
                                              float* __restrict__ out){
  __shared__ float red[1024];
  int tid = threadIdx.x;
  float t = 0.f;
  #pragma unroll
  for (int r = 0; r < 16; ++r){
    int i = r * 4096 + tid * 4;
    float4 u = *(const float4*)(U + i);
    float4 w = *(const float4*)(W + i);
    t += u.x * w.x + u.y * w.y + u.z * w.z + u.w * w.w;
  }
  red[tid] = t; __syncthreads();
  for (int s = 512; s > 0; s >>= 1){ if (tid < s) red[tid] += red[tid + s]; __syncthreads(); }
  if (tid == 0) out[0] = -red[0] / 256.f + scal[2] + scal[3];
}

extern "C" void kernel_launch(void* const* d_in, const int* in_sizes, int n_in,
                              void* d_out, int out_size, void* d_ws, size_t ws_size,
                              hipStream_t stream){
  (void)in_sizes; (void)n_in; (void)out_size;
  const float* X   = (const float*)d_in[0];
  const float* Y   = (const float*)d_in[1];
  const float* mux = (const float*)d_in[2];
  const float* muy = (const float*)d_in[3];
  const float* Wx  = (const float*)d_in[4];
  const float* Wy  = (const float*)d_in[6];
  float* out = (float*)d_out;
  char* ws = (char*)d_ws;

  const size_t MB = 1ull << 20;
  const size_t KB = 1024;
  size_t oXHB = 0;
  size_t oYHB = 32 * MB;
  size_t oWTX = 64 * MB;
  size_t oWTY = oWTX + 512 * KB;
  size_t oSX  = oWTY + 512 * KB;
  size_t oSY  = oSX + 4 * KB;
  size_t oSC  = oSY + 4 * KB;
  size_t oA   = oSC + 4 * KB;
  size_t oB   = oA   + 256 * KB;
  size_t oABF = oB   + 256 * KB;
  size_t oBBF = oABF + 128 * KB;
  size_t oCBF = oBBF + 128 * KB;
  size_t oCBT = oCBF + 128 * KB;
  size_t oX0  = oCBT + 128 * KB;
  size_t oX1  = oX0  + 256 * KB;
  size_t oTB  = oX1  + 256 * KB;
  size_t oU   = oTB  + 256 * KB;
  size_t oV   = oU   + 256 * KB;
  size_t oPart = 68 * MB;

  size_t per = 3ull * 65536 * 4;
  int P = 64;
  while (P > 8 && oPart + (size_t)P * per > ws_size) P >>= 1;

  unsigned short* Xhb = (unsigned short*)(ws + oXHB);
  unsigned short* Yhb = (unsigned short*)(ws + oYHB);
  unsigned short* WTx = (unsigned short*)(ws + oWTX);
  unsigned short* WTy = (unsigned short*)(ws + oWTY);
  float* sx   = (float*)(ws + oSX);
  float* sy   = (float*)(ws + oSY);
  float* scal = (float*)(ws + oSC);
  float* Am   = (float*)(ws + oA);
  float* Bm   = (float*)(ws + oB);
  unsigned short* Abf  = (unsigned short*)(ws + oABF);
  unsigned short* Bbf  = (unsigned short*)(ws + oBBF);
  unsigned short* Cbf  = (unsigned short*)(ws + oCBF);
  unsigned short* CbfT = (unsigned short*)(ws + oCBT);
  unsigned short* X0   = (unsigned short*)(ws + oX0);
  unsigned short* X1   = (unsigned short*)(ws + oX1);
  float* U    = (float*)(ws + oU);
  float* V    = (float*)(ws + oV);
  float* part = (float*)(ws + oPart);

  hipMemsetAsync(ws + oSX, 0, 12 * KB, stream);

  k_prep<<<dim3(256, 2), 256, 0, stream>>>(Wx, Wy, mux, muy, WTx, WTy, scal);
  k_gemm6<<<dim3(1024, 1, 2), 256, 0, stream>>>(X, Y, WTx, WTy, Xhb, Yhb);
  k_gram<<<dim3(P, 1, 3), 512, 0, stream>>>(Xhb, Yhb, part, sx, sy, P);
  k_reduce<<<256, 256, 0, stream>>>(part, sx, sy, Am, Bm, Abf, Bbf, Cbf, CbfT, scal, P);

  k_x1<<<dim3(128, 2), 512, 0, stream>>>(Am, Bm, X0, scal);
  k_it<<<dim3(8, 2), 512, 0, stream>>>(Abf, Bbf, X0, X1);
  k_it<<<dim3(8, 2), 512, 0, stream>>>(Abf, Bbf, X1, X0);
  k_it<<<dim3(8, 2), 512, 0, stream>>>(Abf, Bbf, X0, X1);
  k_it<<<dim3(8, 2), 512, 0, stream>>>(Abf, Bbf, X1, X0);
  k_it<<<dim3(8, 2), 512, 0, stream>>>(Abf, Bbf, X0, X1);   // final in X1
  k_uv<<<dim3(8, 2), 512, 0, stream>>>(X1, Cbf, CbfT, U, V);
  k_fin<<<1, 1024, 0, stream>>>(U, V, scal, out);
}

// Round 8
// 318.339 us; speedup vs baseline: 1.7240x; 1.0738x over previous
//
#include <hip/hip_runtime.h>

#define N_S   65536
#define DXF   1024
#define DD    256
#define NM1   65535.0f
#define EPSR  0.001f

typedef __attribute__((ext_vector_type(4)))  float          f32x4;
typedef __attribute__((ext_vector_type(16))) float          f32x16;
typedef __attribute__((ext_vector_type(8)))  short          bf16x8;
typedef __attribute__((ext_vector_type(4)))  unsigned short ushort4_t;
typedef __attribute__((ext_vector_type(8)))  unsigned short ushort8_t;

__device__ __forceinline__ unsigned short f2bf(float f){
  unsigned u = __float_as_uint(f);
  u += 0x7fffu + ((u >> 16) & 1u);   // RNE
  return (unsigned short)(u >> 16);
}
__device__ __forceinline__ float bf2f(unsigned short h){
  return __uint_as_float(((unsigned)h) << 16);
}
__device__ __forceinline__ f32x4 mfma16(bf16x8 a, bf16x8 b, f32x4 c){
  return __builtin_amdgcn_mfma_f32_16x16x32_bf16(a, b, c, 0, 0, 0);
}
__device__ __forceinline__ f32x16 mfma32(bf16x8 a, bf16x8 b, f32x16 c){
  return __builtin_amdgcn_mfma_f32_32x32x16_bf16(a, b, c, 0, 0, 0);
}
__device__ __forceinline__ void gld_lds16(const void* g, void* l){
  __builtin_amdgcn_global_load_lds(
      (const __attribute__((address_space(1))) unsigned int*)g,
      (__attribute__((address_space(3))) unsigned int*)l, 16, 0, 0);
}

// ------- W' in k-chunk-major bf16 layout + STG regularizer accumulation ----
__global__ void k_prep(const float* __restrict__ Wx, const float* __restrict__ Wy,
                       const float* __restrict__ mux, const float* __restrict__ muy,
                       unsigned short* __restrict__ WTx, unsigned short* __restrict__ WTy,
                       float* __restrict__ scal){
  int v = blockIdx.y;
  const float* W  = v ? Wy  : Wx;
  const float* mu = v ? muy : mux;
  unsigned short* WT = v ? WTy : WTx;
  int j = threadIdx.x;
  if (j < 4){
    float ph = 0.5f * (1.f + erff(mu[blockIdx.x * 4 + j] * 1.41421356237f));
    atomicAdd(scal + 2 + v, 9.765625e-5f * ph);
  }
  #pragma unroll
  for (int r = 0; r < 4; ++r){
    int k = blockIdx.x * 4 + r;
    float g = fminf(fmaxf(mu[k] + 0.5f, 0.f), 1.f);
    WT[(size_t)(k >> 3) * 2048 + j * 8 + (k & 7)] = f2bf(g * W[(size_t)k * DD + j]);
  }
}

// ---------------- big GEMM: Xh = X @ W'  -> bf16 ---------------------------
// 512 thr (8 waves), tile 64x256, wave 16x128, 16x16x32 MFMA.
// 32 acc VGPR/thread -> launch_bounds(512,8): target 32 waves/CU (4 blocks,
// 21KB LDS). Single-buffer B (bank-swizzled via pre-swizzled gld_lds source),
// counted vmcnt keeps A-reg + B prefetch in flight; per-block stalls hidden
// by 31 co-resident waves.
__global__ __launch_bounds__(512, 8) void k_gemm7(
    const float* __restrict__ X, const float* __restrict__ Y,
    const unsigned short* __restrict__ WTx, const unsigned short* __restrict__ WTy,
    unsigned short* __restrict__ Xhb, unsigned short* __restrict__ Yhb){
  const float* A = blockIdx.z ? Y : X;
  const unsigned short* WT = blockIdx.z ? WTy : WTx;
  unsigned short* Out = blockIdx.z ? Yhb : Xhb;

  __shared__ unsigned short As[64][40];        // 5KB
  __shared__ unsigned short Bs[4][256][8];     // 16KB, bank-swizzled layout

  int tid = threadIdx.x, lane = tid & 63, wid = tid >> 6;
  int wr = wid >> 1, wc = wid & 1;
  int row0 = blockIdx.x * 64;

  f32x4 acc[8] = {};

  int s_row = tid >> 3, s_kq = tid & 7;        // 64 rows x 8 float4-slots
  const float* ap = A + (size_t)(row0 + s_row) * DXF + s_kq * 4;

  // B stage: 16 instr (8 waves x 2), chunk = wid&3, colgroup = (wid>>2)*2+i.
  // Physical layout swizzle col'' = col ^ ((col&8)>>1) applied on the SOURCE
  // address (linear LDS dest), read side XORs the same involution.
  auto stageB = [&](int ks){
    #pragma unroll
    for (int i = 0; i < 2; ++i){
      int cl = ((wid >> 2) * 2 + i) * 64 + lane;
      int csw = cl ^ ((cl >> 1) & 4);
      gld_lds16(WT + (size_t)(ks * 4 + (wid & 3)) * 2048 + csw * 8,
                &Bs[wid & 3][((wid >> 2) * 2 + i) * 64][0]);
    }
  };
  auto storeAs = [&](float4 a){
    union { unsigned u[2]; ushort4_t v; } r;
    asm("v_cvt_pk_bf16_f32 %0, %1, %2" : "=v"(r.u[0]) : "v"(a.x), "v"(a.y));
    asm("v_cvt_pk_bf16_f32 %0, %1, %2" : "=v"(r.u[1]) : "v"(a.z), "v"(a.w));
    *(ushort4_t*)&As[s_row][s_kq * 4] = r.v;
  };

  // swizzled per-thread B-frag base (XOR is lane-constant, folded here)
  const unsigned short* bb = &Bs[0][0][0] + (lane >> 4) * 2048 + wc * 1024
                           + (((lane & 15) * 8) ^ ((lane & 8) << 2));

  float4 a0;
  stageB(0);
  asm volatile("" ::: "memory");
  a0 = *(const float4*)(ap);
  asm volatile("s_waitcnt vmcnt(0)" ::: "memory");
  storeAs(a0);
  a0 = *(const float4*)(ap + 32);
  asm volatile("s_waitcnt lgkmcnt(0)" ::: "memory");
  __builtin_amdgcn_s_barrier();

  for (int ks = 0; ks < 32; ++ks){
    bf16x8 af = *(const bf16x8*)&As[wr * 16 + (lane & 15)][(lane >> 4) * 8];
    #pragma unroll
    for (int ni = 0; ni < 8; ++ni){
      bf16x8 bf = *(const bf16x8*)(bb + ni * 128);
      acc[ni] = mfma16(af, bf, acc[ni]);
    }
    if (ks == 31) break;
    __builtin_amdgcn_s_barrier();            // all waves done reading As/Bs
    stageB(ks + 1);                          // +2/wave
    asm volatile("s_waitcnt vmcnt(2)" ::: "memory");   // A(ks+1) regs ready
    storeAs(a0);
    if (ks + 2 < 32){
      a0 = *(const float4*)(ap + (ks + 2) * 32);       // +1/wave
      asm volatile("s_waitcnt vmcnt(1)" ::: "memory"); // B(ks+1) arrived
    } else {
      asm volatile("s_waitcnt vmcnt(0)" ::: "memory");
    }
    asm volatile("s_waitcnt lgkmcnt(0)" ::: "memory");
    __builtin_amdgcn_s_barrier();
  }

  // epilogue: 2-pass LDS transpose (16KB in Bs) -> coalesced bf16 stores
  __syncthreads();
  unsigned short* tl = &Bs[0][0][0];
  #pragma unroll
  for (int p = 0; p < 2; ++p){
    if ((wr >> 1) == p){
      #pragma unroll
      for (int ni = 0; ni < 8; ++ni)
        #pragma unroll
        for (int rr = 0; rr < 4; ++rr){
          int r = (wr & 1) * 16 + (lane >> 4) * 4 + rr;
          int c = wc * 128 + ni * 16 + (lane & 15);
          tl[r * 256 + c] = f2bf(acc[ni][rr]);
        }
    }
    __syncthreads();
    unsigned short* ob = Out + (size_t)(row0 + p * 32) * DD;
    #pragma unroll
    for (int r = 0; r < 2; ++r){
      int off = r * 4096 + tid * 8;
      *(ushort8_t*)(ob + off) = *(const ushort8_t*)(tl + off);
    }
    if (p == 0) __syncthreads();
  }
}

// ---------------- Gram kernel: split-K partials (unchanged) ----------------
__global__ __launch_bounds__(512) void k_gram(
    const unsigned short* __restrict__ Xhb, const unsigned short* __restrict__ Yhb,
    float* __restrict__ part, float* __restrict__ sx, float* __restrict__ sy, int P){
  int type = blockIdx.z;
  int p = blockIdx.x;
  int chunk = N_S / P;
  int r0 = p * chunk;
  const unsigned short* Asrc = (type == 0) ? Xhb : Yhb;
  const unsigned short* Bsrc = (type == 1) ? Yhb : Xhb;
  bool dualB = (type == 2);

  __shared__ unsigned short At[256][40];
  __shared__ unsigned short Bt[256][40];

  int tid = threadIdx.x;
  int lane = tid & 63, wid = tid >> 6;
  int wr = wid >> 1, wc = wid & 1;

  f32x4 acc[4][8] = {};
  float cs0 = 0.f, cs1 = 0.f;

  int cp  = tid & 127;
  int kb0 = tid >> 7;

  unsigned ua[2][4], ub[2][4];

  auto loadT = [&](int ks){
    int base = r0 + ks * 32;
    #pragma unroll
    for (int r = 0; r < 2; ++r){
      int kb = kb0 + r * 4;
      #pragma unroll
      for (int kr = 0; kr < 4; ++kr){
        ua[r][kr] = *(const unsigned*)(Asrc + (size_t)(base + kb * 4 + kr) * DD + cp * 2);
        if (dualB)
          ub[r][kr] = *(const unsigned*)(Bsrc + (size_t)(base + kb * 4 + kr) * DD + cp * 2);
      }
    }
  };
  auto storeT = [&](){
    #pragma unroll
    for (int r = 0; r < 2; ++r){
      int kb = kb0 + r * 4;
      ushort4_t lo = { (unsigned short)ua[r][0], (unsigned short)ua[r][1],
                       (unsigned short)ua[r][2], (unsigned short)ua[r][3] };
      ushort4_t hi = { (unsigned short)(ua[r][0] >> 16), (unsigned short)(ua[r][1] >> 16),
                       (unsigned short)(ua[r][2] >> 16), (unsigned short)(ua[r][3] >> 16) };
      *(ushort4_t*)&At[cp * 2][kb * 4]     = lo;
      *(ushort4_t*)&At[cp * 2 + 1][kb * 4] = hi;
      if (type < 2){
        #pragma unroll
        for (int kr = 0; kr < 4; ++kr){
          cs0 += bf2f((unsigned short)ua[r][kr]);
          cs1 += bf2f((unsigned short)(ua[r][kr] >> 16));
        }
      }
      if (dualB){
        ushort4_t lob = { (unsigned short)ub[r][0], (unsigned short)ub[r][1],
                          (unsigned short)ub[r][2], (unsigned short)ub[r][3] };
        ushort4_t hib = { (unsigned short)(ub[r][0] >> 16), (unsigned short)(ub[r][1] >> 16),
                          (unsigned short)(ub[r][2] >> 16), (unsigned short)(ub[r][3] >> 16) };
        *(ushort4_t*)&Bt[cp * 2][kb * 4]     = lob;
        *(ushort4_t*)&Bt[cp * 2 + 1][kb * 4] = hib;
      }
    }
  };

  unsigned short (*Btp)[40] = dualB ? Bt : At;

  int KS = chunk / 32;
  loadT(0);
  for (int ks = 0; ks < KS; ++ks){
    __syncthreads();
    storeT();
    __syncthreads();
    if (ks + 1 < KS) loadT(ks + 1);
    bf16x8 af[4], bfv[8];
    #pragma unroll
    for (int mi = 0; mi < 4; ++mi)
      af[mi] = *(const bf16x8*)&At[wr * 64 + mi * 16 + (lane & 15)][(lane >> 4) * 8];
    #pragma unroll
    for (int ni = 0; ni < 8; ++ni)
      bfv[ni] = *(const bf16x8*)&Btp[wc * 128 + ni * 16 + (lane & 15)][(lane >> 4) * 8];
    #pragma unroll
    for (int mi = 0; mi < 4; ++mi)
      #pragma unroll
      for (int ni = 0; ni < 8; ++ni)
        acc[mi][ni] = mfma16(af[mi], bfv[ni], acc[mi][ni]);
  }

  float* dst = part + ((size_t)p * 3 + type) * 65536;
  #pragma unroll
  for (int mi = 0; mi < 4; ++mi)
    #pragma unroll
    for (int ni = 0; ni < 8; ++ni)
      #pragma unroll
      for (int rr = 0; rr < 4; ++rr){
        int grow = wr * 64 + mi * 16 + (lane >> 4) * 4 + rr;
        int gcol = wc * 128 + ni * 16 + (lane & 15);
        dst[(size_t)grow * 256 + gcol] = acc[mi][ni][rr];
      }

  if (type < 2){
    __syncthreads();
    float* red = (float*)&At[0][0];
    red[kb0 * 256 + cp * 2]     = cs0;
    red[kb0 * 256 + cp * 2 + 1] = cs1;
    __syncthreads();
    if (tid < 256){
      float s = red[tid] + red[256 + tid] + red[512 + tid] + red[768 + tid];
      atomicAdd((type == 0 ? sx : sy) + tid, s);
    }
  }
}

// -------- reduce partials -> A,B (fp32+bf16), C bf16(+T), inf-norms --------
__global__ void k_reduce(const float* __restrict__ part, const float* __restrict__ sx,
                         const float* __restrict__ sy, float* __restrict__ Am,
                         float* __restrict__ Bm,
                         unsigned short* __restrict__ Abf, unsigned short* __restrict__ Bbf,
                         unsigned short* __restrict__ Cbf, unsigned short* __restrict__ CbfT,
                         float* __restrict__ scal, int P){
  __shared__ float r2[256];
  int i = blockIdx.x, j = threadIdx.x;
  size_t idx = (size_t)i * 256 + j;
  float gxx = 0.f, gyy = 0.f, gyx = 0.f;
  for (int p = 0; p < P; ++p){
    const float* b = part + (size_t)p * 3 * 65536;
    gxx += b[idx];
    gyy += b[65536 + idx];
    gyx += b[131072 + idx];
  }
  float invn1 = 1.f / NM1;
  float invn  = 1.f / (float)N_S;
  float sxi = sx[i], sxj = sx[j], syi = sy[i], syj = sy[j];
  float diag = (i == j) ? 1.f : 0.f;
  float am = (gyy - syi * syj * invn) * invn1 + diag * (2.f * EPSR);
  float bm = (gxx - sxi * sxj * invn) * invn1 + diag * EPSR;
  float cv = (gyx - syi * sxj * invn) * invn1;
  Am[idx] = am;  Bm[idx] = bm;
  Abf[idx] = f2bf(am);
  Bbf[idx] = f2bf(bm);
  Cbf[idx] = f2bf(cv);
  CbfT[(size_t)j * 256 + i] = f2bf(cv);
  r2[j] = fabsf(am);
  __syncthreads();
  for (int s = 128; s > 0; s >>= 1){ if (j < s) r2[j] += r2[j + s]; __syncthreads(); }
  if (j == 0) atomicMax((unsigned*)scal + 5, __float_as_uint(r2[0]));
  __syncthreads();
  r2[j] = fabsf(bm);
  __syncthreads();
  for (int s = 128; s > 0; s >>= 1){ if (j < s) r2[j] += r2[j + s]; __syncthreads(); }
  if (j == 0) atomicMax((unsigned*)scal + 6, __float_as_uint(r2[0]));
}

// -------- X1 = 2aI - a^2 M  (NS step 1 closed form), a = 1.9/||M||inf ------
__global__ void k_x1(const float* __restrict__ Am, const float* __restrict__ Bm,
                     unsigned short* __restrict__ X0, const float* __restrict__ scal){
  int m = blockIdx.y;
  const unsigned* su = (const unsigned*)scal;
  float al = 1.9f / __uint_as_float(su[5 + m]);
  const float* M = m ? Bm : Am;
  int e = blockIdx.x * 512 + threadIdx.x;
  float v = -al * al * M[e];
  if ((e >> 8) == (e & 255)) v += 2.f * al;
  X0[m * 65536 + e] = f2bf(v);
}

// -------- one NS iteration, col-block local: X'_j = 2X_j - X*(M*X_j) -------
__global__ __launch_bounds__(512) void k_it(
    const unsigned short* __restrict__ Abf, const unsigned short* __restrict__ Bbf,
    const unsigned short* __restrict__ Xc, unsigned short* __restrict__ Xn){
  int m = blockIdx.y, j = blockIdx.x;
  const unsigned short* M  = m ? Bbf : Abf;
  const unsigned short* Xm = Xc + m * 65536;
  unsigned short*       Xo = Xn + m * 65536;

  __shared__ unsigned short XJ[32 * 256];
  __shared__ unsigned short TT[32 * 256];

  int tid = threadIdx.x, lane = tid & 63, w = tid >> 6;
  int r31 = lane & 31, kh = lane >> 5;

  #pragma unroll
  for (int i = 0; i < 2; ++i){
    int rl = w * 4 + i * 2 + kh;
    int cg = ((lane & 31) - rl) & 31;
    gld_lds16(Xm + (size_t)(j * 32 + rl) * 256 + cg * 8, &XJ[(w * 4 + i * 2) * 256]);
  }
  asm volatile("s_waitcnt vmcnt(0)" ::: "memory");
  __builtin_amdgcn_s_barrier();

  f32x16 acc = {};
  const unsigned short* arow = M + (size_t)(w * 32 + r31) * 256 + kh * 8;
  #pragma unroll
  for (int ks = 0; ks < 16; ++ks){
    bf16x8 af = *(const bf16x8*)(arow + ks * 16);
    int ch = ((ks * 2 + kh) + r31) & 31;
    bf16x8 bf = *(const bf16x8*)&XJ[r31 * 256 + ch * 8];
    acc = mfma32(af, bf, acc);
  }
  #pragma unroll
  for (int reg = 0; reg < 16; ++reg){
    int kk = w * 32 + (reg & 3) + ((reg >> 2) << 3) + (kh << 2);
    int ch = ((kk >> 3) + r31) & 31;
    TT[r31 * 256 + ch * 8 + (kk & 7)] = f2bf(acc[reg]);
  }
  __syncthreads();

  f32x16 acc2 = {};
  const unsigned short* xrow = Xm + (size_t)(w * 32 + r31) * 256 + kh * 8;
  #pragma unroll
  for (int ks = 0; ks < 16; ++ks){
    bf16x8 af = *(const bf16x8*)(xrow + ks * 16);
    int ch = ((ks * 2 + kh) + r31) & 31;
    bf16x8 bf = *(const bf16x8*)&TT[r31 * 256 + ch * 8];
    acc2 = mfma32(af, bf, acc2);
  }
  #pragma unroll
  for (int reg = 0; reg < 16; ++reg){
    int row = w * 32 + (reg & 3) + ((reg >> 2) << 3) + (kh << 2);
    int ch = ((row >> 3) + r31) & 31;
    float xv = bf2f(XJ[r31 * 256 + ch * 8 + (row & 7)]);
    Xo[(size_t)row * 256 + j * 32 + r31] = f2bf(2.f * xv - acc2[reg]);
  }
}

// -------- U = XA*C (mat0) ; W = C*XB = V^T (mat1) ; f32 outputs ------------
__global__ __launch_bounds__(512) void k_uv(
    const unsigned short* __restrict__ Xf,
    const unsigned short* __restrict__ Cbf, const unsigned short* __restrict__ CbfT,
    float* __restrict__ U, float* __restrict__ W){
  int m = blockIdx.y, j = blockIdx.x;
  __shared__ unsigned short BJ[32 * 256];
  int tid = threadIdx.x, lane = tid & 63, w = tid >> 6;
  int r31 = lane & 31, kh = lane >> 5;
  const unsigned short* Brows = m ? (Xf + 65536) : CbfT;
  const unsigned short* Arows = m ? Cbf : Xf;
  float* D = m ? W : U;

  #pragma unroll
  for (int i = 0; i < 2; ++i){
    int rl = w * 4 + i * 2 + kh;
    int cg = ((lane & 31) - rl) & 31;
    gld_lds16(Brows + (size_t)(j * 32 + rl) * 256 + cg * 8, &BJ[(w * 4 + i * 2) * 256]);
  }
  asm volatile("s_waitcnt vmcnt(0)" ::: "memory");
  __builtin_amdgcn_s_barrier();

  f32x16 acc = {};
  const unsigned short* ar = Arows + (size_t)(w * 32 + r31) * 256 + kh * 8;
  #pragma unroll
  for (int ks = 0; ks < 16; ++ks){
    bf16x8 af = *(const bf16x8*)(ar + ks * 16);
    int ch = ((ks * 2 + kh) + r31) & 31;
    bf16x8 bf = *(const bf16x8*)&BJ[r31 * 256 + ch * 8];
    acc = mfma32(af, bf, acc);
  }
  #pragma unroll
  for (int reg = 0; reg < 16; ++reg){
    int row = w * 32 + (reg & 3) + ((reg >> 2) << 3) + (kh << 2);
    D[(size_t)row * 256 + j * 32 + r31] = acc[reg];
  }
}

// -------- final: loss = -sum(U*W)/256 + regx + regy ------------------------
__global__ __launch_bounds__(1024) void k_fin(const float* __restrict__ U,
                                              const float* __restrict__ W,
                                              const float* __restrict__ scal,
                                              float* __restrict__ out){
  __shared__ float red[1024];
  int tid = threadIdx.x;
  float t = 0.f;
  #pragma unroll
  for (int r = 0; r < 16; ++r){
    int i = r * 4096 + tid * 4;
    float4 u = *(const float4*)(U + i);
    float4 w = *(const float4*)(W + i);
    t += u.x * w.x + u.y * w.y + u.z * w.z + u.w * w.w;
  }
  red[tid] = t; __syncthreads();
  for (int s = 512; s > 0; s >>= 1){ if (tid < s) red[tid] += red[tid + s]; __syncthreads(); }
  if (tid == 0) out[0] = -red[0] / 256.f + scal[2] + scal[3];
}

extern "C" void kernel_launch(void* const* d_in, const int* in_sizes, int n_in,
                              void* d_out, int out_size, void* d_ws, size_t ws_size,
                              hipStream_t stream){
  (void)in_sizes; (void)n_in; (void)out_size;
  const float* X   = (const float*)d_in[0];
  const float* Y   = (const float*)d_in[1];
  const float* mux = (const float*)d_in[2];
  const float* muy = (const float*)d_in[3];
  const float* Wx  = (const float*)d_in[4];
  const float* Wy  = (const float*)d_in[6];
  float* out = (float*)d_out;
  char* ws = (char*)d_ws;

  const size_t MB = 1ull << 20;
  const size_t KB = 1024;
  size_t oXHB = 0;
  size_t oYHB = 32 * MB;
  size_t oWTX = 64 * MB;
  size_t oWTY = oWTX + 512 * KB;
  size_t oSX  = oWTY + 512 * KB;
  size_t oSY  = oSX + 4 * KB;
  size_t oSC  = oSY + 4 * KB;
  size_t oA   = oSC + 4 * KB;
  size_t oB   = oA   + 256 * KB;
  size_t oABF = oB   + 256 * KB;
  size_t oBBF = oABF + 128 * KB;
  size_t oCBF = oBBF + 128 * KB;
  size_t oCBT = oCBF + 128 * KB;
  size_t oX0  = oCBT + 128 * KB;
  size_t oX1  = oX0  + 256 * KB;
  size_t oTB  = oX1  + 256 * KB;
  size_t oU   = oTB  + 256 * KB;
  size_t oV   = oU   + 256 * KB;
  size_t oPart = 68 * MB;

  size_t per = 3ull * 65536 * 4;
  int P = 64;
  while (P > 8 && oPart + (size_t)P * per > ws_size) P >>= 1;

  unsigned short* Xhb = (unsigned short*)(ws + oXHB);
  unsigned short* Yhb = (unsigned short*)(ws + oYHB);
  unsigned short* WTx = (unsigned short*)(ws + oWTX);
  unsigned short* WTy = (unsigned short*)(ws + oWTY);
  float* sx   = (float*)(ws + oSX);
  float* sy   = (float*)(ws + oSY);
  float* scal = (float*)(ws + oSC);
  float* Am   = (float*)(ws + oA);
  float* Bm   = (float*)(ws + oB);
  unsigned short* Abf  = (unsigned short*)(ws + oABF);
  unsigned short* Bbf  = (unsigned short*)(ws + oBBF);
  unsigned short* Cbf  = (unsigned short*)(ws + oCBF);
  unsigned short* CbfT = (unsigned short*)(ws + oCBT);
  unsigned short* X0   = (unsigned short*)(ws + oX0);
  unsigned short* X1   = (unsigned short*)(ws + oX1);
  float* U    = (float*)(ws + oU);
  float* V    = (float*)(ws + oV);
  float* part = (float*)(ws + oPart);

  hipMemsetAsync(ws + oSX, 0, 12 * KB, stream);

  k_prep<<<dim3(256, 2), 256, 0, stream>>>(Wx, Wy, mux, muy, WTx, WTy, scal);
  k_gemm7<<<dim3(1024, 1, 2), 512, 0, stream>>>(X, Y, WTx, WTy, Xhb, Yhb);
  k_gram<<<dim3(P, 1, 3), 512, 0, stream>>>(Xhb, Yhb, part, sx, sy, P);
  k_reduce<<<256, 256, 0, stream>>>(part, sx, sy, Am, Bm, Abf, Bbf, Cbf, CbfT, scal, P);

  k_x1<<<dim3(128, 2), 512, 0, stream>>>(Am, Bm, X0, scal);
  k_it<<<dim3(8, 2), 512, 0, stream>>>(Abf, Bbf, X0, X1);
  k_it<<<dim3(8, 2), 512, 0, stream>>>(Abf, Bbf, X1, X0);
  k_it<<<dim3(8, 2), 512, 0, stream>>>(Abf, Bbf, X0, X1);
  k_it<<<dim3(8, 2), 512, 0, stream>>>(Abf, Bbf, X1, X0);
  k_it<<<dim3(8, 2), 512, 0, stream>>>(Abf, Bbf, X0, X1);   // final in X1
  k_uv<<<dim3(8, 2), 512, 0, stream>>>(X1, Cbf, CbfT, U, V);
  k_fin<<<1, 1024, 0, stream>>>(U, V, scal, out);
}

// Round 9
// 307.879 us; speedup vs baseline: 1.7826x; 1.0340x over previous
//
#include <hip/hip_runtime.h>

#define N_S   65536
#define DXF   1024
#define DD    256
#define NM1   65535.0f
#define EPSR  0.001f

typedef __attribute__((ext_vector_type(4)))  float          f32x4;
typedef __attribute__((ext_vector_type(16))) float          f32x16;
typedef __attribute__((ext_vector_type(8)))  short          bf16x8;
typedef __attribute__((ext_vector_type(4)))  unsigned short ushort4_t;
typedef __attribute__((ext_vector_type(8)))  unsigned short ushort8_t;

__device__ __forceinline__ unsigned short f2bf(float f){
  unsigned u = __float_as_uint(f);
  u += 0x7fffu + ((u >> 16) & 1u);   // RNE
  return (unsigned short)(u >> 16);
}
__device__ __forceinline__ float bf2f(unsigned short h){
  return __uint_as_float(((unsigned)h) << 16);
}
__device__ __forceinline__ f32x4 mfma16(bf16x8 a, bf16x8 b, f32x4 c){
  return __builtin_amdgcn_mfma_f32_16x16x32_bf16(a, b, c, 0, 0, 0);
}
__device__ __forceinline__ f32x16 mfma32(bf16x8 a, bf16x8 b, f32x16 c){
  return __builtin_amdgcn_mfma_f32_32x32x16_bf16(a, b, c, 0, 0, 0);
}
__device__ __forceinline__ void gld_lds16(const void* g, void* l){
  __builtin_amdgcn_global_load_lds(
      (const __attribute__((address_space(1))) unsigned int*)g,
      (__attribute__((address_space(3))) unsigned int*)l, 16, 0, 0);
}

// ------- W' in k-chunk-major bf16 layout + STG regularizer accumulation ----
__global__ void k_prep(const float* __restrict__ Wx, const float* __restrict__ Wy,
                       const float* __restrict__ mux, const float* __restrict__ muy,
                       unsigned short* __restrict__ WTx, unsigned short* __restrict__ WTy,
                       float* __restrict__ scal){
  int v = blockIdx.y;
  const float* W  = v ? Wy  : Wx;
  const float* mu = v ? muy : mux;
  unsigned short* WT = v ? WTy : WTx;
  int j = threadIdx.x;
  if (j < 4){
    float ph = 0.5f * (1.f + erff(mu[blockIdx.x * 4 + j] * 1.41421356237f));
    atomicAdd(scal + 2 + v, 9.765625e-5f * ph);
  }
  #pragma unroll
  for (int r = 0; r < 4; ++r){
    int k = blockIdx.x * 4 + r;
    float g = fminf(fmaxf(mu[k] + 0.5f, 0.f), 1.f);
    WT[(size_t)(k >> 3) * 2048 + j * 8 + (k & 7)] = f2bf(g * W[(size_t)k * DD + j]);
  }
}

// ---------------- big GEMM: Xh = X @ W'  -> bf16 ---------------------------
// 512 thr (8 waves, 2x4), tile 64x256, wave tile 32x64 (square-ish: min LDS
// fragment traffic 48KB/step vs 72KB at 16x128). B double-buffered (stage
// issued one full iteration before its wait). 37KB LDS, VGPR<=64 -> 4
// blocks/CU = 32 waves (84%+ occ).
__global__ __launch_bounds__(512, 8) void k_gemm8(
    const float* __restrict__ X, const float* __restrict__ Y,
    const unsigned short* __restrict__ WTx, const unsigned short* __restrict__ WTy,
    unsigned short* __restrict__ Xhb, unsigned short* __restrict__ Yhb){
  const float* A = blockIdx.z ? Y : X;
  const unsigned short* WT = blockIdx.z ? WTy : WTx;
  unsigned short* Out = blockIdx.z ? Yhb : Xhb;

  __shared__ unsigned short As[64][40];          // 5KB
  __shared__ unsigned short Bs[2][4][256][8];    // 32KB dbuf

  int tid = threadIdx.x, lane = tid & 63, wid = tid >> 6;
  int wr = wid >> 2, wc = wid & 3;               // 2 x 4 wave grid
  int row0 = blockIdx.x * 64;

  f32x4 acc[2][4] = {};

  int s_row = tid >> 3, s_kq = tid & 7;          // 64 rows x 8 float4-slots
  const float* ap = A + (size_t)(row0 + s_row) * DXF + s_kq * 4;

  // B stage: 16 instr (8 waves x 2): chunk = wid&3, colgroup = (wid>>2)*2+i
  auto stageB = [&](int buf, int ks){
    #pragma unroll
    for (int i = 0; i < 2; ++i){
      int cg = (wid >> 2) * 2 + i;
      gld_lds16(WT + (size_t)(ks * 4 + (wid & 3)) * 2048 + (cg * 64 + lane) * 8,
                &Bs[buf][wid & 3][cg * 64][0]);
    }
  };
  auto storeAs = [&](float4 a){
    union { unsigned u[2]; ushort4_t v; } r;
    asm("v_cvt_pk_bf16_f32 %0, %1, %2" : "=v"(r.u[0]) : "v"(a.x), "v"(a.y));
    asm("v_cvt_pk_bf16_f32 %0, %1, %2" : "=v"(r.u[1]) : "v"(a.z), "v"(a.w));
    *(ushort4_t*)&As[s_row][s_kq * 4] = r.v;
  };

  float4 a0, ar;
  stageB(0, 0);                                   // 2 out
  asm volatile("" ::: "memory");
  a0 = *(const float4*)(ap);                      // 3 out
  asm volatile("" ::: "memory");
  stageB(1, 1);                                   // 5 out
  asm volatile("s_waitcnt vmcnt(2)" ::: "memory");  // B(0)+A(0) done
  storeAs(a0);
  ar = *(const float4*)(ap + 32);                 // A(1); out: B1(2)+A1(1)
  asm volatile("s_waitcnt lgkmcnt(0)" ::: "memory");
  __builtin_amdgcn_s_barrier();

  for (int ks = 0; ks < 32; ++ks){
    int buf = ks & 1;
    bf16x8 af0 = *(const bf16x8*)&As[wr * 32 + (lane & 15)][(lane >> 4) * 8];
    bf16x8 af1 = *(const bf16x8*)&As[wr * 32 + 16 + (lane & 15)][(lane >> 4) * 8];
    #pragma unroll
    for (int ni = 0; ni < 4; ++ni){
      bf16x8 bf = *(const bf16x8*)&Bs[buf][lane >> 4][wc * 64 + ni * 16 + (lane & 15)][0];
      acc[0][ni] = mfma16(af0, bf, acc[0][ni]);
      acc[1][ni] = mfma16(af1, bf, acc[1][ni]);
    }
    if (ks == 31) break;
    __builtin_amdgcn_s_barrier();                 // all waves done with As/Bs[buf]
    if (ks + 2 < 32){
      stageB(buf, ks + 2);                        // out: B(k+1)2 A(k+1)1 B(k+2)2
      asm volatile("s_waitcnt vmcnt(2)" ::: "memory");  // A(k+1)+B(k+1) done
    } else {
      asm volatile("s_waitcnt vmcnt(0)" ::: "memory");
    }
    storeAs(ar);
    if (ks + 2 < 32){
      asm volatile("" ::: "memory");
      ar = *(const float4*)(ap + (ks + 2) * 32);  // A(k+2)
    }
    asm volatile("s_waitcnt lgkmcnt(0)" ::: "memory");
    __builtin_amdgcn_s_barrier();
  }

  // epilogue: single-pass LDS transpose (32KB in Bs) -> coalesced stores
  __syncthreads();
  unsigned short* tl = &Bs[0][0][0][0];
  #pragma unroll
  for (int mi = 0; mi < 2; ++mi)
    #pragma unroll
    for (int ni = 0; ni < 4; ++ni)
      #pragma unroll
      for (int rr = 0; rr < 4; ++rr){
        int r = wr * 32 + mi * 16 + (lane >> 4) * 4 + rr;
        int c = wc * 64 + ni * 16 + (lane & 15);
        tl[r * 256 + c] = f2bf(acc[mi][ni][rr]);
      }
  __syncthreads();
  unsigned short* ob = Out + (size_t)row0 * DD;
  #pragma unroll
  for (int r = 0; r < 4; ++r){
    int off = r * 4096 + tid * 8;
    *(ushort8_t*)(ob + off) = *(const ushort8_t*)(tl + off);
  }
}

// ---------------- Gram kernel: split-K partials (unchanged) ----------------
__global__ __launch_bounds__(512) void k_gram(
    const unsigned short* __restrict__ Xhb, const unsigned short* __restrict__ Yhb,
    float* __restrict__ part, float* __restrict__ sx, float* __restrict__ sy, int P){
  int type = blockIdx.z;
  int p = blockIdx.x;
  int chunk = N_S / P;
  int r0 = p * chunk;
  const unsigned short* Asrc = (type == 0) ? Xhb : Yhb;
  const unsigned short* Bsrc = (type == 1) ? Yhb : Xhb;
  bool dualB = (type == 2);

  __shared__ unsigned short At[256][40];
  __shared__ unsigned short Bt[256][40];

  int tid = threadIdx.x;
  int lane = tid & 63, wid = tid >> 6;
  int wr = wid >> 1, wc = wid & 1;

  f32x4 acc[4][8] = {};
  float cs0 = 0.f, cs1 = 0.f;

  int cp  = tid & 127;
  int kb0 = tid >> 7;

  unsigned ua[2][4], ub[2][4];

  auto loadT = [&](int ks){
    int base = r0 + ks * 32;
    #pragma unroll
    for (int r = 0; r < 2; ++r){
      int kb = kb0 + r * 4;
      #pragma unroll
      for (int kr = 0; kr < 4; ++kr){
        ua[r][kr] = *(const unsigned*)(Asrc + (size_t)(base + kb * 4 + kr) * DD + cp * 2);
        if (dualB)
          ub[r][kr] = *(const unsigned*)(Bsrc + (size_t)(base + kb * 4 + kr) * DD + cp * 2);
      }
    }
  };
  auto storeT = [&](){
    #pragma unroll
    for (int r = 0; r < 2; ++r){
      int kb = kb0 + r * 4;
      ushort4_t lo = { (unsigned short)ua[r][0], (unsigned short)ua[r][1],
                       (unsigned short)ua[r][2], (unsigned short)ua[r][3] };
      ushort4_t hi = { (unsigned short)(ua[r][0] >> 16), (unsigned short)(ua[r][1] >> 16),
                       (unsigned short)(ua[r][2] >> 16), (unsigned short)(ua[r][3] >> 16) };
      *(ushort4_t*)&At[cp * 2][kb * 4]     = lo;
      *(ushort4_t*)&At[cp * 2 + 1][kb * 4] = hi;
      if (type < 2){
        #pragma unroll
        for (int kr = 0; kr < 4; ++kr){
          cs0 += bf2f((unsigned short)ua[r][kr]);
          cs1 += bf2f((unsigned short)(ua[r][kr] >> 16));
        }
      }
      if (dualB){
        ushort4_t lob = { (unsigned short)ub[r][0], (unsigned short)ub[r][1],
                          (unsigned short)ub[r][2], (unsigned short)ub[r][3] };
        ushort4_t hib = { (unsigned short)(ub[r][0] >> 16), (unsigned short)(ub[r][1] >> 16),
                          (unsigned short)(ub[r][2] >> 16), (unsigned short)(ub[r][3] >> 16) };
        *(ushort4_t*)&Bt[cp * 2][kb * 4]     = lob;
        *(ushort4_t*)&Bt[cp * 2 + 1][kb * 4] = hib;
      }
    }
  };

  unsigned short (*Btp)[40] = dualB ? Bt : At;

  int KS = chunk / 32;
  loadT(0);
  for (int ks = 0; ks < KS; ++ks){
    __syncthreads();
    storeT();
    __syncthreads();
    if (ks + 1 < KS) loadT(ks + 1);
    bf16x8 af[4], bfv[8];
    #pragma unroll
    for (int mi = 0; mi < 4; ++mi)
      af[mi] = *(const bf16x8*)&At[wr * 64 + mi * 16 + (lane & 15)][(lane >> 4) * 8];
    #pragma unroll
    for (int ni = 0; ni < 8; ++ni)
      bfv[ni] = *(const bf16x8*)&Btp[wc * 128 + ni * 16 + (lane & 15)][(lane >> 4) * 8];
    #pragma unroll
    for (int mi = 0; mi < 4; ++mi)
      #pragma unroll
      for (int ni = 0; ni < 8; ++ni)
        acc[mi][ni] = mfma16(af[mi], bfv[ni], acc[mi][ni]);
  }

  float* dst = part + ((size_t)p * 3 + type) * 65536;
  #pragma unroll
  for (int mi = 0; mi < 4; ++mi)
    #pragma unroll
    for (int ni = 0; ni < 8; ++ni)
      #pragma unroll
      for (int rr = 0; rr < 4; ++rr){
        int grow = wr * 64 + mi * 16 + (lane >> 4) * 4 + rr;
        int gcol = wc * 128 + ni * 16 + (lane & 15);
        dst[(size_t)grow * 256 + gcol] = acc[mi][ni][rr];
      }

  if (type < 2){
    __syncthreads();
    float* red = (float*)&At[0][0];
    red[kb0 * 256 + cp * 2]     = cs0;
    red[kb0 * 256 + cp * 2 + 1] = cs1;
    __syncthreads();
    if (tid < 256){
      float s = red[tid] + red[256 + tid] + red[512 + tid] + red[768 + tid];
      atomicAdd((type == 0 ? sx : sy) + tid, s);
    }
  }
}

// -------- reduce partials -> A,B (fp32+bf16), C bf16(+T), inf-norms --------
__global__ void k_reduce(const float* __restrict__ part, const float* __restrict__ sx,
                         const float* __restrict__ sy, float* __restrict__ Am,
                         float* __restrict__ Bm,
                         unsigned short* __restrict__ Abf, unsigned short* __restrict__ Bbf,
                         unsigned short* __restrict__ Cbf, unsigned short* __restrict__ CbfT,
                         float* __restrict__ scal, int P){
  __shared__ float r2[256];
  int i = blockIdx.x, j = threadIdx.x;
  size_t idx = (size_t)i * 256 + j;
  float gxx = 0.f, gyy = 0.f, gyx = 0.f;
  for (int p = 0; p < P; ++p){
    const float* b = part + (size_t)p * 3 * 65536;
    gxx += b[idx];
    gyy += b[65536 + idx];
    gyx += b[131072 + idx];
  }
  float invn1 = 1.f / NM1;
  float invn  = 1.f / (float)N_S;
  float sxi = sx[i], sxj = sx[j], syi = sy[i], syj = sy[j];
  float diag = (i == j) ? 1.f : 0.f;
  float am = (gyy - syi * syj * invn) * invn1 + diag * (2.f * EPSR);
  float bm = (gxx - sxi * sxj * invn) * invn1 + diag * EPSR;
  float cv = (gyx - syi * sxj * invn) * invn1;
  Am[idx] = am;  Bm[idx] = bm;
  Abf[idx] = f2bf(am);
  Bbf[idx] = f2bf(bm);
  Cbf[idx] = f2bf(cv);
  CbfT[(size_t)j * 256 + i] = f2bf(cv);
  r2[j] = fabsf(am);
  __syncthreads();
  for (int s = 128; s > 0; s >>= 1){ if (j < s) r2[j] += r2[j + s]; __syncthreads(); }
  if (j == 0) atomicMax((unsigned*)scal + 5, __float_as_uint(r2[0]));
  __syncthreads();
  r2[j] = fabsf(bm);
  __syncthreads();
  for (int s = 128; s > 0; s >>= 1){ if (j < s) r2[j] += r2[j + s]; __syncthreads(); }
  if (j == 0) atomicMax((unsigned*)scal + 6, __float_as_uint(r2[0]));
}

// -------- X1 = 2aI - a^2 M  (NS step 1 closed form), a = 1.9/||M||inf ------
__global__ void k_x1(const float* __restrict__ Am, const float* __restrict__ Bm,
                     unsigned short* __restrict__ X0, const float* __restrict__ scal){
  int m = blockIdx.y;
  const unsigned* su = (const unsigned*)scal;
  float al = 1.9f / __uint_as_float(su[5 + m]);
  const float* M = m ? Bm : Am;
  int e = blockIdx.x * 512 + threadIdx.x;
  float v = -al * al * M[e];
  if ((e >> 8) == (e & 255)) v += 2.f * al;
  X0[m * 65536 + e] = f2bf(v);
}

// -------- one NS iteration, col-block local: X'_j = 2X_j - X*(M*X_j) -------
__global__ __launch_bounds__(512) void k_it(
    const unsigned short* __restrict__ Abf, const unsigned short* __restrict__ Bbf,
    const unsigned short* __restrict__ Xc, unsigned short* __restrict__ Xn){
  int m = blockIdx.y, j = blockIdx.x;
  const unsigned short* M  = m ? Bbf : Abf;
  const unsigned short* Xm = Xc + m * 65536;
  unsigned short*       Xo = Xn + m * 65536;

  __shared__ unsigned short XJ[32 * 256];
  __shared__ unsigned short TT[32 * 256];

  int tid = threadIdx.x, lane = tid & 63, w = tid >> 6;
  int r31 = lane & 31, kh = lane >> 5;

  #pragma unroll
  for (int i = 0; i < 2; ++i){
    int rl = w * 4 + i * 2 + kh;
    int cg = ((lane & 31) - rl) & 31;
    gld_lds16(Xm + (size_t)(j * 32 + rl) * 256 + cg * 8, &XJ[(w * 4 + i * 2) * 256]);
  }
  asm volatile("s_waitcnt vmcnt(0)" ::: "memory");
  __builtin_amdgcn_s_barrier();

  f32x16 acc = {};
  const unsigned short* arow = M + (size_t)(w * 32 + r31) * 256 + kh * 8;
  #pragma unroll
  for (int ks = 0; ks < 16; ++ks){
    bf16x8 af = *(const bf16x8*)(arow + ks * 16);
    int ch = ((ks * 2 + kh) + r31) & 31;
    bf16x8 bf = *(const bf16x8*)&XJ[r31 * 256 + ch * 8];
    acc = mfma32(af, bf, acc);
  }
  #pragma unroll
  for (int reg = 0; reg < 16; ++reg){
    int kk = w * 32 + (reg & 3) + ((reg >> 2) << 3) + (kh << 2);
    int ch = ((kk >> 3) + r31) & 31;
    TT[r31 * 256 + ch * 8 + (kk & 7)] = f2bf(acc[reg]);
  }
  __syncthreads();

  f32x16 acc2 = {};
  const unsigned short* xrow = Xm + (size_t)(w * 32 + r31) * 256 + kh * 8;
  #pragma unroll
  for (int ks = 0; ks < 16; ++ks){
    bf16x8 af = *(const bf16x8*)(xrow + ks * 16);
    int ch = ((ks * 2 + kh) + r31) & 31;
    bf16x8 bf = *(const bf16x8*)&TT[r31 * 256 + ch * 8];
    acc2 = mfma32(af, bf, acc2);
  }
  #pragma unroll
  for (int reg = 0; reg < 16; ++reg){
    int row = w * 32 + (reg & 3) + ((reg >> 2) << 3) + (kh << 2);
    int ch = ((row >> 3) + r31) & 31;
    float xv = bf2f(XJ[r31 * 256 + ch * 8 + (row & 7)]);
    Xo[(size_t)row * 256 + j * 32 + r31] = f2bf(2.f * xv - acc2[reg]);
  }
}

// -------- U = XA*C (mat0) ; W = C*XB = V^T (mat1) ; f32 outputs ------------
__global__ __launch_bounds__(512) void k_uv(
    const unsigned short* __restrict__ Xf,
    const unsigned short* __restrict__ Cbf, const unsigned short* __restrict__ CbfT,
    float* __restrict__ U, float* __restrict__ W){
  int m = blockIdx.y, j = blockIdx.x;
  __shared__ unsigned short BJ[32 * 256];
  int tid = threadIdx.x, lane = tid & 63, w = tid >> 6;
  int r31 = lane & 31, kh = lane >> 5;
  const unsigned short* Brows = m ? (Xf + 65536) : CbfT;
  const unsigned short* Arows = m ? Cbf : Xf;
  float* D = m ? W : U;

  #pragma unroll
  for (int i = 0; i < 2; ++i){
    int rl = w * 4 + i * 2 + kh;
    int cg = ((lane & 31) - rl) & 31;
    gld_lds16(Brows + (size_t)(j * 32 + rl) * 256 + cg * 8, &BJ[(w * 4 + i * 2) * 256]);
  }
  asm volatile("s_waitcnt vmcnt(0)" ::: "memory");
  __builtin_amdgcn_s_barrier();

  f32x16 acc = {};
  const unsigned short* ar = Arows + (size_t)(w * 32 + r31) * 256 + kh * 8;
  #pragma unroll
  for (int ks = 0; ks < 16; ++ks){
    bf16x8 af = *(const bf16x8*)(ar + ks * 16);
    int ch = ((ks * 2 + kh) + r31) & 31;
    bf16x8 bf = *(const bf16x8*)&BJ[r31 * 256 + ch * 8];
    acc = mfma32(af, bf, acc);
  }
  #pragma unroll
  for (int reg = 0; reg < 16; ++reg){
    int row = w * 32 + (reg & 3) + ((reg >> 2) << 3) + (kh << 2);
    D[(size_t)row * 256 + j * 32 + r31] = acc[reg];
  }
}

// -------- final: loss = -sum(U*W)/256 + regx + regy ------------------------
__global__ __launch_bounds__(1024) void k_fin(const float* __restrict__ U,
                                              const float* __restrict__ W,
                                              const float* __restrict__ scal,
                                              float* __restrict__ out){
  __shared__ float red[1024];
  int tid = threadIdx.x;
  float t = 0.f;
  #pragma unroll
  for (int r = 0; r < 16; ++r){
    int i = r * 4096 + tid * 4;
    float4 u = *(const float4*)(U + i);
    float4 w = *(const float4*)(W + i);
    t += u.x * w.x + u.y * w.y + u.z * w.z + u.w * w.w;
  }
  red[tid] = t; __syncthreads();
  for (int s = 512; s > 0; s >>= 1){ if (tid < s) red[tid] += red[tid + s]; __syncthreads(); }
  if (tid == 0) out[0] = -red[0] / 256.f + scal[2] + scal[3];
}

extern "C" void kernel_launch(void* const* d_in, const int* in_sizes, int n_in,
                              void* d_out, int out_size, void* d_ws, size_t ws_size,
                              hipStream_t stream){
  (void)in_sizes; (void)n_in; (void)out_size;
  const float* X   = (const float*)d_in[0];
  const float* Y   = (const float*)d_in[1];
  const float* mux = (const float*)d_in[2];
  const float* muy = (const float*)d_in[3];
  const float* Wx  = (const float*)d_in[4];
  const float* Wy  = (const float*)d_in[6];
  float* out = (float*)d_out;
  char* ws = (char*)d_ws;

  const size_t MB = 1ull << 20;
  const size_t KB = 1024;
  size_t oXHB = 0;
  size_t oYHB = 32 * MB;
  size_t oWTX = 64 * MB;
  size_t oWTY = oWTX + 512 * KB;
  size_t oSX  = oWTY + 512 * KB;
  size_t oSY  = oSX + 4 * KB;
  size_t oSC  = oSY + 4 * KB;
  size_t oA   = oSC + 4 * KB;
  size_t oB   = oA   + 256 * KB;
  size_t oABF = oB   + 256 * KB;
  size_t oBBF = oABF + 128 * KB;
  size_t oCBF = oBBF + 128 * KB;
  size_t oCBT = oCBF + 128 * KB;
  size_t oX0  = oCBT + 128 * KB;
  size_t oX1  = oX0  + 256 * KB;
  size_t oTB  = oX1  + 256 * KB;
  size_t oU   = oTB  + 256 * KB;
  size_t oV   = oU   + 256 * KB;
  size_t oPart = 68 * MB;

  size_t per = 3ull * 65536 * 4;
  int P = 64;
  while (P > 8 && oPart + (size_t)P * per > ws_size) P >>= 1;

  unsigned short* Xhb = (unsigned short*)(ws + oXHB);
  unsigned short* Yhb = (unsigned short*)(ws + oYHB);
  unsigned short* WTx = (unsigned short*)(ws + oWTX);
  unsigned short* WTy = (unsigned short*)(ws + oWTY);
  float* sx   = (float*)(ws + oSX);
  float* sy   = (float*)(ws + oSY);
  float* scal = (float*)(ws + oSC);
  float* Am   = (float*)(ws + oA);
  float* Bm   = (float*)(ws + oB);
  unsigned short* Abf  = (unsigned short*)(ws + oABF);
  unsigned short* Bbf  = (unsigned short*)(ws + oBBF);
  unsigned short* Cbf  = (unsigned short*)(ws + oCBF);
  unsigned short* CbfT = (unsigned short*)(ws + oCBT);
  unsigned short* X0   = (unsigned short*)(ws + oX0);
  unsigned short* X1   = (unsigned short*)(ws + oX1);
  float* U    = (float*)(ws + oU);
  float* V    = (float*)(ws + oV);
  float* part = (float*)(ws + oPart);

  hipMemsetAsync(ws + oSX, 0, 12 * KB, stream);

  k_prep<<<dim3(256, 2), 256, 0, stream>>>(Wx, Wy, mux, muy, WTx, WTy, scal);
  k_gemm8<<<dim3(1024, 1, 2), 512, 0, stream>>>(X, Y, WTx, WTy, Xhb, Yhb);
  k_gram<<<dim3(P, 1, 3), 512, 0, stream>>>(Xhb, Yhb, part, sx, sy, P);
  k_reduce<<<256, 256, 0, stream>>>(part, sx, sy, Am, Bm, Abf, Bbf, Cbf, CbfT, scal, P);

  k_x1<<<dim3(128, 2), 512, 0, stream>>>(Am, Bm, X0, scal);
  k_it<<<dim3(8, 2), 512, 0, stream>>>(Abf, Bbf, X0, X1);
  k_it<<<dim3(8, 2), 512, 0, stream>>>(Abf, Bbf, X1, X0);
  k_it<<<dim3(8, 2), 512, 0, stream>>>(Abf, Bbf, X0, X1);
  k_it<<<dim3(8, 2), 512, 0, stream>>>(Abf, Bbf, X1, X0);
  k_it<<<dim3(8, 2), 512, 0, stream>>>(Abf, Bbf, X0, X1);   // final in X1
  k_uv<<<dim3(8, 2), 512, 0, stream>>>(X1, Cbf, CbfT, U, V);
  k_fin<<<1, 1024, 0, stream>>>(U, V, scal, out);
}

// Round 10
// 286.098 us; speedup vs baseline: 1.9183x; 1.0761x over previous
//
#include <hip/hip_runtime.h>

#define N_S   65536
#define DXF   1024
#define DD    256
#define NM1   65535.0f
#define EPSR  0.001f

typedef __attribute__((ext_vector_type(4)))  float          f32x4;
typedef __attribute__((ext_vector_type(16))) float          f32x16;
typedef __attribute__((ext_vector_type(8)))  short          bf16x8;
typedef __attribute__((ext_vector_type(4)))  unsigned short ushort4_t;
typedef __attribute__((ext_vector_type(8)))  unsigned short ushort8_t;

__device__ __forceinline__ unsigned short f2bf(float f){
  unsigned u = __float_as_uint(f);
  u += 0x7fffu + ((u >> 16) & 1u);   // RNE
  return (unsigned short)(u >> 16);
}
__device__ __forceinline__ float bf2f(unsigned short h){
  return __uint_as_float(((unsigned)h) << 16);
}
__device__ __forceinline__ f32x4 mfma16(bf16x8 a, bf16x8 b, f32x4 c){
  return __builtin_amdgcn_mfma_f32_16x16x32_bf16(a, b, c, 0, 0, 0);
}
__device__ __forceinline__ f32x16 mfma32(bf16x8 a, bf16x8 b, f32x16 c){
  return __builtin_amdgcn_mfma_f32_32x32x16_bf16(a, b, c, 0, 0, 0);
}
__device__ __forceinline__ void gld_lds16(const void* g, void* l){
  __builtin_amdgcn_global_load_lds(
      (const __attribute__((address_space(1))) unsigned int*)g,
      (__attribute__((address_space(3))) unsigned int*)l, 16, 0, 0);
}

#define VMCNT(N) asm volatile("s_waitcnt vmcnt(" #N ")" ::: "memory")

// ------- W' in k-chunk-major bf16 layout + STG regularizer accumulation ----
__global__ void k_prep(const float* __restrict__ Wx, const float* __restrict__ Wy,
                       const float* __restrict__ mux, const float* __restrict__ muy,
                       unsigned short* __restrict__ WTx, unsigned short* __restrict__ WTy,
                       float* __restrict__ scal){
  int v = blockIdx.y;
  const float* W  = v ? Wy  : Wx;
  const float* mu = v ? muy : mux;
  unsigned short* WT = v ? WTy : WTx;
  int j = threadIdx.x;
  if (j < 4){
    float ph = 0.5f * (1.f + erff(mu[blockIdx.x * 4 + j] * 1.41421356237f));
    atomicAdd(scal + 2 + v, 9.765625e-5f * ph);
  }
  #pragma unroll
  for (int r = 0; r < 4; ++r){
    int k = blockIdx.x * 4 + r;
    float g = fminf(fmaxf(mu[k] + 0.5f, 0.f), 1.f);
    WT[(size_t)(k >> 3) * 2048 + j * 8 + (k & 7)] = f2bf(g * W[(size_t)k * DD + j]);
  }
}

// ---------------- big GEMM: Xh = X @ W'  -> bf16 ---------------------------
// 512 thr (8 waves 1x8), tile 64x256, wave tile 64x32.
// A: K-chunks of 128 (512B/row-visit -> DRAM page hits), bf16 dbuf LDS.
// B: NO LDS - 8 bf16x8 frags per chunk loaded L2->regs at chunk top.
// 1 barrier per chunk (8 total). Counted vmcnt + sched_barrier(0).
__global__ __launch_bounds__(512, 4) void k_gemm9(
    const float* __restrict__ X, const float* __restrict__ Y,
    const unsigned short* __restrict__ WTx, const unsigned short* __restrict__ WTy,
    unsigned short* __restrict__ Xhb, unsigned short* __restrict__ Yhb){
  const float* A = blockIdx.z ? Y : X;
  const unsigned short* WT = blockIdx.z ? WTy : WTx;
  unsigned short* Out = blockIdx.z ? Yhb : Xhb;

  __shared__ unsigned short As[2][64][136];    // 34.8KB, 16B rows, ~2-way banks

  int tid = threadIdx.x, lane = tid & 63, wid = tid >> 6;
  int row0 = blockIdx.x * 64;

  f32x4 acc[4][2] = {};

  int s_row = tid >> 3, s_f4 = tid & 7;        // 64 rows x 8 f4-slots (x4 iters)
  const float* ap = A + (size_t)(row0 + s_row) * DXF + s_f4 * 4;

  // B fragment base: col = wid*32 + t*16 + (lane&15); k-group = (lane>>4)
  const unsigned short* bB = WT + (size_t)(lane >> 4) * 2048
                           + (wid * 32 + (lane & 15)) * 8;

  float4 ar0, ar1, ar2, ar3;
  auto writeA = [&](int b){
    union { unsigned u[2]; ushort4_t v; } w;
    asm("v_cvt_pk_bf16_f32 %0, %1, %2" : "=v"(w.u[0]) : "v"(ar0.x), "v"(ar0.y));
    asm("v_cvt_pk_bf16_f32 %0, %1, %2" : "=v"(w.u[1]) : "v"(ar0.z), "v"(ar0.w));
    *(ushort4_t*)&As[b][s_row][s_f4 * 4] = w.v;
    asm("v_cvt_pk_bf16_f32 %0, %1, %2" : "=v"(w.u[0]) : "v"(ar1.x), "v"(ar1.y));
    asm("v_cvt_pk_bf16_f32 %0, %1, %2" : "=v"(w.u[1]) : "v"(ar1.z), "v"(ar1.w));
    *(ushort4_t*)&As[b][s_row][s_f4 * 4 + 32] = w.v;
    asm("v_cvt_pk_bf16_f32 %0, %1, %2" : "=v"(w.u[0]) : "v"(ar2.x), "v"(ar2.y));
    asm("v_cvt_pk_bf16_f32 %0, %1, %2" : "=v"(w.u[1]) : "v"(ar2.z), "v"(ar2.w));
    *(ushort4_t*)&As[b][s_row][s_f4 * 4 + 64] = w.v;
    asm("v_cvt_pk_bf16_f32 %0, %1, %2" : "=v"(w.u[0]) : "v"(ar3.x), "v"(ar3.y));
    asm("v_cvt_pk_bf16_f32 %0, %1, %2" : "=v"(w.u[1]) : "v"(ar3.z), "v"(ar3.w));
    *(ushort4_t*)&As[b][s_row][s_f4 * 4 + 96] = w.v;
  };
  auto loadA = [&](int kc){
    const float* p = ap + kc * 128;
    ar0 = *(const float4*)(p);
    ar1 = *(const float4*)(p + 32);
    ar2 = *(const float4*)(p + 64);
    ar3 = *(const float4*)(p + 96);
  };

  // prologue: chunk 0 staged synchronously
  loadA(0);
  VMCNT(0);
  writeA(0);
  asm volatile("s_waitcnt lgkmcnt(0)" ::: "memory");
  __builtin_amdgcn_s_barrier();

#define GSTEP(S, BA, BB) { \
    bf16x8 af0 = *(const bf16x8*)&As[buf][     (lane & 15)][S * 32 + (lane >> 4) * 8]; \
    bf16x8 af1 = *(const bf16x8*)&As[buf][16 + (lane & 15)][S * 32 + (lane >> 4) * 8]; \
    bf16x8 af2 = *(const bf16x8*)&As[buf][32 + (lane & 15)][S * 32 + (lane >> 4) * 8]; \
    bf16x8 af3 = *(const bf16x8*)&As[buf][48 + (lane & 15)][S * 32 + (lane >> 4) * 8]; \
    acc[0][0] = mfma16(af0, BA, acc[0][0]); acc[0][1] = mfma16(af0, BB, acc[0][1]); \
    acc[1][0] = mfma16(af1, BA, acc[1][0]); acc[1][1] = mfma16(af1, BB, acc[1][1]); \
    acc[2][0] = mfma16(af2, BA, acc[2][0]); acc[2][1] = mfma16(af2, BB, acc[2][1]); \
    acc[3][0] = mfma16(af3, BA, acc[3][0]); acc[3][1] = mfma16(af3, BB, acc[3][1]); }

  #pragma unroll
  for (int c = 0; c < 8; ++c){
    int buf = c & 1;
    const unsigned short* bc = bB + c * 32768;
    // issue all 8 B-frags of this chunk (L2 hits), THEN A prefetch
    bf16x8 b0a = *(const bf16x8*)(bc);
    bf16x8 b0b = *(const bf16x8*)(bc + 128);
    bf16x8 b1a = *(const bf16x8*)(bc + 8192);
    bf16x8 b1b = *(const bf16x8*)(bc + 8320);
    bf16x8 b2a = *(const bf16x8*)(bc + 16384);
    bf16x8 b2b = *(const bf16x8*)(bc + 16512);
    bf16x8 b3a = *(const bf16x8*)(bc + 24576);
    bf16x8 b3b = *(const bf16x8*)(bc + 24704);
    asm volatile("" ::: "memory");
    if (c < 7) loadA(c + 1);                   // 4 loads, newest

    if (c < 7) { VMCNT(10); } else { VMCNT(6); }   // B(s0) ready
    __builtin_amdgcn_sched_barrier(0);
    GSTEP(0, b0a, b0b)
    if (c < 7) { VMCNT(8); } else { VMCNT(4); }
    __builtin_amdgcn_sched_barrier(0);
    GSTEP(1, b1a, b1b)
    if (c < 7) { VMCNT(6); } else { VMCNT(2); }
    __builtin_amdgcn_sched_barrier(0);
    GSTEP(2, b2a, b2b)
    if (c < 7) { VMCNT(4); } else { VMCNT(0); }
    __builtin_amdgcn_sched_barrier(0);
    GSTEP(3, b3a, b3b)

    if (c < 7){
      VMCNT(0);                                // A(c+1) regs ready
      __builtin_amdgcn_sched_barrier(0);
      writeA(buf ^ 1);
      asm volatile("s_waitcnt lgkmcnt(0)" ::: "memory");
      __builtin_amdgcn_s_barrier();
    }
  }
#undef GSTEP

  // epilogue: LDS transpose (32KB in As) -> coalesced bf16 stores
  __syncthreads();
  unsigned short* tl = &As[0][0][0];
  #pragma unroll
  for (int r = 0; r < 4; ++r)
    #pragma unroll
    for (int t = 0; t < 2; ++t)
      #pragma unroll
      for (int rr = 0; rr < 4; ++rr){
        int row = r * 16 + (lane >> 4) * 4 + rr;
        int col = wid * 32 + t * 16 + (lane & 15);
        tl[row * 256 + col] = f2bf(acc[r][t][rr]);
      }
  __syncthreads();
  unsigned short* ob = Out + (size_t)row0 * DD;
  #pragma unroll
  for (int r = 0; r < 4; ++r){
    int off = r * 4096 + tid * 8;
    *(ushort8_t*)(ob + off) = *(const ushort8_t*)(tl + off);
  }
}

// ---------------- Gram kernel: split-K partials (unchanged) ----------------
__global__ __launch_bounds__(512) void k_gram(
    const unsigned short* __restrict__ Xhb, const unsigned short* __restrict__ Yhb,
    float* __restrict__ part, float* __restrict__ sx, float* __restrict__ sy, int P){
  int type = blockIdx.z;
  int p = blockIdx.x;
  int chunk = N_S / P;
  int r0 = p * chunk;
  const unsigned short* Asrc = (type == 0) ? Xhb : Yhb;
  const unsigned short* Bsrc = (type == 1) ? Yhb : Xhb;
  bool dualB = (type == 2);

  __shared__ unsigned short At[256][40];
  __shared__ unsigned short Bt[256][40];

  int tid = threadIdx.x;
  int lane = tid & 63, wid = tid >> 6;
  int wr = wid >> 1, wc = wid & 1;

  f32x4 acc[4][8] = {};
  float cs0 = 0.f, cs1 = 0.f;

  int cp  = tid & 127;
  int kb0 = tid >> 7;

  unsigned ua[2][4], ub[2][4];

  auto loadT = [&](int ks){
    int base = r0 + ks * 32;
    #pragma unroll
    for (int r = 0; r < 2; ++r){
      int kb = kb0 + r * 4;
      #pragma unroll
      for (int kr = 0; kr < 4; ++kr){
        ua[r][kr] = *(const unsigned*)(Asrc + (size_t)(base + kb * 4 + kr) * DD + cp * 2);
        if (dualB)
          ub[r][kr] = *(const unsigned*)(Bsrc + (size_t)(base + kb * 4 + kr) * DD + cp * 2);
      }
    }
  };
  auto storeT = [&](){
    #pragma unroll
    for (int r = 0; r < 2; ++r){
      int kb = kb0 + r * 4;
      ushort4_t lo = { (unsigned short)ua[r][0], (unsigned short)ua[r][1],
                       (unsigned short)ua[r][2], (unsigned short)ua[r][3] };
      ushort4_t hi = { (unsigned short)(ua[r][0] >> 16), (unsigned short)(ua[r][1] >> 16),
                       (unsigned short)(ua[r][2] >> 16), (unsigned short)(ua[r][3] >> 16) };
      *(ushort4_t*)&At[cp * 2][kb * 4]     = lo;
      *(ushort4_t*)&At[cp * 2 + 1][kb * 4] = hi;
      if (type < 2){
        #pragma unroll
        for (int kr = 0; kr < 4; ++kr){
          cs0 += bf2f((unsigned short)ua[r][kr]);
          cs1 += bf2f((unsigned short)(ua[r][kr] >> 16));
        }
      }
      if (dualB){
        ushort4_t lob = { (unsigned short)ub[r][0], (unsigned short)ub[r][1],
                          (unsigned short)ub[r][2], (unsigned short)ub[r][3] };
        ushort4_t hib = { (unsigned short)(ub[r][0] >> 16), (unsigned short)(ub[r][1] >> 16),
                          (unsigned short)(ub[r][2] >> 16), (unsigned short)(ub[r][3] >> 16) };
        *(ushort4_t*)&Bt[cp * 2][kb * 4]     = lob;
        *(ushort4_t*)&Bt[cp * 2 + 1][kb * 4] = hib;
      }
    }
  };

  unsigned short (*Btp)[40] = dualB ? Bt : At;

  int KS = chunk / 32;
  loadT(0);
  for (int ks = 0; ks < KS; ++ks){
    __syncthreads();
    storeT();
    __syncthreads();
    if (ks + 1 < KS) loadT(ks + 1);
    bf16x8 af[4], bfv[8];
    #pragma unroll
    for (int mi = 0; mi < 4; ++mi)
      af[mi] = *(const bf16x8*)&At[wr * 64 + mi * 16 + (lane & 15)][(lane >> 4) * 8];
    #pragma unroll
    for (int ni = 0; ni < 8; ++ni)
      bfv[ni] = *(const bf16x8*)&Btp[wc * 128 + ni * 16 + (lane & 15)][(lane >> 4) * 8];
    #pragma unroll
    for (int mi = 0; mi < 4; ++mi)
      #pragma unroll
      for (int ni = 0; ni < 8; ++ni)
        acc[mi][ni] = mfma16(af[mi], bfv[ni], acc[mi][ni]);
  }

  float* dst = part + ((size_t)p * 3 + type) * 65536;
  #pragma unroll
  for (int mi = 0; mi < 4; ++mi)
    #pragma unroll
    for (int ni = 0; ni < 8; ++ni)
      #pragma unroll
      for (int rr = 0; rr < 4; ++rr){
        int grow = wr * 64 + mi * 16 + (lane >> 4) * 4 + rr;
        int gcol = wc * 128 + ni * 16 + (lane & 15);
        dst[(size_t)grow * 256 + gcol] = acc[mi][ni][rr];
      }

  if (type < 2){
    __syncthreads();
    float* red = (float*)&At[0][0];
    red[kb0 * 256 + cp * 2]     = cs0;
    red[kb0 * 256 + cp * 2 + 1] = cs1;
    __syncthreads();
    if (tid < 256){
      float s = red[tid] + red[256 + tid] + red[512 + tid] + red[768 + tid];
      atomicAdd((type == 0 ? sx : sy) + tid, s);
    }
  }
}

// -------- reduce partials -> A,B (fp32+bf16), C bf16(+T), inf-norms --------
__global__ void k_reduce(const float* __restrict__ part, const float* __restrict__ sx,
                         const float* __restrict__ sy, float* __restrict__ Am,
                         float* __restrict__ Bm,
                         unsigned short* __restrict__ Abf, unsigned short* __restrict__ Bbf,
                         unsigned short* __restrict__ Cbf, unsigned short* __restrict__ CbfT,
                         float* __restrict__ scal, int P){
  __shared__ float r2[256];
  int i = blockIdx.x, j = threadIdx.x;
  size_t idx = (size_t)i * 256 + j;
  float gxx = 0.f, gyy = 0.f, gyx = 0.f;
  for (int p = 0; p < P; ++p){
    const float* b = part + (size_t)p * 3 * 65536;
    gxx += b[idx];
    gyy += b[65536 + idx];
    gyx += b[131072 + idx];
  }
  float invn1 = 1.f / NM1;
  float invn  = 1.f / (float)N_S;
  float sxi = sx[i], sxj = sx[j], syi = sy[i], syj = sy[j];
  float diag = (i == j) ? 1.f : 0.f;
  float am = (gyy - syi * syj * invn) * invn1 + diag * (2.f * EPSR);
  float bm = (gxx - sxi * sxj * invn) * invn1 + diag * EPSR;
  float cv = (gyx - syi * sxj * invn) * invn1;
  Am[idx] = am;  Bm[idx] = bm;
  Abf[idx] = f2bf(am);
  Bbf[idx] = f2bf(bm);
  Cbf[idx] = f2bf(cv);
  CbfT[(size_t)j * 256 + i] = f2bf(cv);
  r2[j] = fabsf(am);
  __syncthreads();
  for (int s = 128; s > 0; s >>= 1){ if (j < s) r2[j] += r2[j + s]; __syncthreads(); }
  if (j == 0) atomicMax((unsigned*)scal + 5, __float_as_uint(r2[0]));
  __syncthreads();
  r2[j] = fabsf(bm);
  __syncthreads();
  for (int s = 128; s > 0; s >>= 1){ if (j < s) r2[j] += r2[j + s]; __syncthreads(); }
  if (j == 0) atomicMax((unsigned*)scal + 6, __float_as_uint(r2[0]));
}

// -------- X1 = 2aI - a^2 M  (NS step 1 closed form), a = 1.9/||M||inf ------
__global__ void k_x1(const float* __restrict__ Am, const float* __restrict__ Bm,
                     unsigned short* __restrict__ X0, const float* __restrict__ scal){
  int m = blockIdx.y;
  const unsigned* su = (const unsigned*)scal;
  float al = 1.9f / __uint_as_float(su[5 + m]);
  const float* M = m ? Bm : Am;
  int e = blockIdx.x * 512 + threadIdx.x;
  float v = -al * al * M[e];
  if ((e >> 8) == (e & 255)) v += 2.f * al;
  X0[m * 65536 + e] = f2bf(v);
}

// -------- one NS iteration, col-block local: X'_j = 2X_j - X*(M*X_j) -------
__global__ __launch_bounds__(512) void k_it(
    const unsigned short* __restrict__ Abf, const unsigned short* __restrict__ Bbf,
    const unsigned short* __restrict__ Xc, unsigned short* __restrict__ Xn){
  int m = blockIdx.y, j = blockIdx.x;
  const unsigned short* M  = m ? Bbf : Abf;
  const unsigned short* Xm = Xc + m * 65536;
  unsigned short*       Xo = Xn + m * 65536;

  __shared__ unsigned short XJ[32 * 256];
  __shared__ unsigned short TT[32 * 256];

  int tid = threadIdx.x, lane = tid & 63, w = tid >> 6;
  int r31 = lane & 31, kh = lane >> 5;

  #pragma unroll
  for (int i = 0; i < 2; ++i){
    int rl = w * 4 + i * 2 + kh;
    int cg = ((lane & 31) - rl) & 31;
    gld_lds16(Xm + (size_t)(j * 32 + rl) * 256 + cg * 8, &XJ[(w * 4 + i * 2) * 256]);
  }
  asm volatile("s_waitcnt vmcnt(0)" ::: "memory");
  __builtin_amdgcn_s_barrier();

  f32x16 acc = {};
  const unsigned short* arow = M + (size_t)(w * 32 + r31) * 256 + kh * 8;
  #pragma unroll
  for (int ks = 0; ks < 16; ++ks){
    bf16x8 af = *(const bf16x8*)(arow + ks * 16);
    int ch = ((ks * 2 + kh) + r31) & 31;
    bf16x8 bf = *(const bf16x8*)&XJ[r31 * 256 + ch * 8];
    acc = mfma32(af, bf, acc);
  }
  #pragma unroll
  for (int reg = 0; reg < 16; ++reg){
    int kk = w * 32 + (reg & 3) + ((reg >> 2) << 3) + (kh << 2);
    int ch = ((kk >> 3) + r31) & 31;
    TT[r31 * 256 + ch * 8 + (kk & 7)] = f2bf(acc[reg]);
  }
  __syncthreads();

  f32x16 acc2 = {};
  const unsigned short* xrow = Xm + (size_t)(w * 32 + r31) * 256 + kh * 8;
  #pragma unroll
  for (int ks = 0; ks < 16; ++ks){
    bf16x8 af = *(const bf16x8*)(xrow + ks * 16);
    int ch = ((ks * 2 + kh) + r31) & 31;
    bf16x8 bf = *(const bf16x8*)&TT[r31 * 256 + ch * 8];
    acc2 = mfma32(af, bf, acc2);
  }
  #pragma unroll
  for (int reg = 0; reg < 16; ++reg){
    int row = w * 32 + (reg & 3) + ((reg >> 2) << 3) + (kh << 2);
    int ch = ((row >> 3) + r31) & 31;
    float xv = bf2f(XJ[r31 * 256 + ch * 8 + (row & 7)]);
    Xo[(size_t)row * 256 + j * 32 + r31] = f2bf(2.f * xv - acc2[reg]);
  }
}

// -------- U = XA*C (mat0) ; W = C*XB = V^T (mat1) ; f32 outputs ------------
__global__ __launch_bounds__(512) void k_uv(
    const unsigned short* __restrict__ Xf,
    const unsigned short* __restrict__ Cbf, const unsigned short* __restrict__ CbfT,
    float* __restrict__ U, float* __restrict__ W){
  int m = blockIdx.y, j = blockIdx.x;
  __shared__ unsigned short BJ[32 * 256];
  int tid = threadIdx.x, lane = tid & 63, w = tid >> 6;
  int r31 = lane & 31, kh = lane >> 5;
  const unsigned short* Brows = m ? (Xf + 65536) : CbfT;
  const unsigned short* Arows = m ? Cbf : Xf;
  float* D = m ? W : U;

  #pragma unroll
  for (int i = 0; i < 2; ++i){
    int rl = w * 4 + i * 2 + kh;
    int cg = ((lane & 31) - rl) & 31;
    gld_lds16(Brows + (size_t)(j * 32 + rl) * 256 + cg * 8, &BJ[(w * 4 + i * 2) * 256]);
  }
  asm volatile("s_waitcnt vmcnt(0)" ::: "memory");
  __builtin_amdgcn_s_barrier();

  f32x16 acc = {};
  const unsigned short* ar = Arows + (size_t)(w * 32 + r31) * 256 + kh * 8;
  #pragma unroll
  for (int ks = 0; ks < 16; ++ks){
    bf16x8 af = *(const bf16x8*)(ar + ks * 16);
    int ch = ((ks * 2 + kh) + r31) & 31;
    bf16x8 bf = *(const bf16x8*)&BJ[r31 * 256 + ch * 8];
    acc = mfma32(af, bf, acc);
  }
  #pragma unroll
  for (int reg = 0; reg < 16; ++reg){
    int row = w * 32 + (reg & 3) + ((reg >> 2) << 3) + (kh << 2);
    D[(size_t)row * 256 + j * 32 + r31] = acc[reg];
  }
}

// -------- final: loss = -sum(U*W)/256 + regx + regy ------------------------
__global__ __launch_bounds__(1024) void k_fin(const float* __restrict__ U,
                                              const float* __restrict__ W,
                                              const float* __restrict__ scal,
                                              float* __restrict__ out){
  __shared__ float red[1024];
  int tid = threadIdx.x;
  float t = 0.f;
  #pragma unroll
  for (int r = 0; r < 16; ++r){
    int i = r * 4096 + tid * 4;
    float4 u = *(const float4*)(U + i);
    float4 w = *(const float4*)(W + i);
    t += u.x * w.x + u.y * w.y + u.z * w.z + u.w * w.w;
  }
  red[tid] = t; __syncthreads();
  for (int s = 512; s > 0; s >>= 1){ if (tid < s) red[tid] += red[tid + s]; __syncthreads(); }
  if (tid == 0) out[0] = -red[0] / 256.f + scal[2] + scal[3];
}

extern "C" void kernel_launch(void* const* d_in, const int* in_sizes, int n_in,
                              void* d_out, int out_size, void* d_ws, size_t ws_size,
                              hipStream_t stream){
  (void)in_sizes; (void)n_in; (void)out_size;
  const float* X   = (const float*)d_in[0];
  const float* Y   = (const float*)d_in[1];
  const float* mux = (const float*)d_in[2];
  const float* muy = (const float*)d_in[3];
  const float* Wx  = (const float*)d_in[4];
  const float* Wy  = (const float*)d_in[6];
  float* out = (float*)d_out;
  char* ws = (char*)d_ws;

  const size_t MB = 1ull << 20;
  const size_t KB = 1024;
  size_t oXHB = 0;
  size_t oYHB = 32 * MB;
  size_t oWTX = 64 * MB;
  size_t oWTY = oWTX + 512 * KB;
  size_t oSX  = oWTY + 512 * KB;
  size_t oSY  = oSX + 4 * KB;
  size_t oSC  = oSY + 4 * KB;
  size_t oA   = oSC + 4 * KB;
  size_t oB   = oA   + 256 * KB;
  size_t oABF = oB   + 256 * KB;
  size_t oBBF = oABF + 128 * KB;
  size_t oCBF = oBBF + 128 * KB;
  size_t oCBT = oCBF + 128 * KB;
  size_t oX0  = oCBT + 128 * KB;
  size_t oX1  = oX0  + 256 * KB;
  size_t oTB  = oX1  + 256 * KB;
  size_t oU   = oTB  + 256 * KB;
  size_t oV   = oU   + 256 * KB;
  size_t oPart = 68 * MB;

  size_t per = 3ull * 65536 * 4;
  int P = 64;
  while (P > 8 && oPart + (size_t)P * per > ws_size) P >>= 1;

  unsigned short* Xhb = (unsigned short*)(ws + oXHB);
  unsigned short* Yhb = (unsigned short*)(ws + oYHB);
  unsigned short* WTx = (unsigned short*)(ws + oWTX);
  unsigned short* WTy = (unsigned short*)(ws + oWTY);
  float* sx   = (float*)(ws + oSX);
  float* sy   = (float*)(ws + oSY);
  float* scal = (float*)(ws + oSC);
  float* Am   = (float*)(ws + oA);
  float* Bm   = (float*)(ws + oB);
  unsigned short* Abf  = (unsigned short*)(ws + oABF);
  unsigned short* Bbf  = (unsigned short*)(ws + oBBF);
  unsigned short* Cbf  = (unsigned short*)(ws + oCBF);
  unsigned short* CbfT = (unsigned short*)(ws + oCBT);
  unsigned short* X0   = (unsigned short*)(ws + oX0);
  unsigned short* X1   = (unsigned short*)(ws + oX1);
  float* U    = (float*)(ws + oU);
  float* V    = (float*)(ws + oV);
  float* part = (float*)(ws + oPart);

  hipMemsetAsync(ws + oSX, 0, 12 * KB, stream);

  k_prep<<<dim3(256, 2), 256, 0, stream>>>(Wx, Wy, mux, muy, WTx, WTy, scal);
  k_gemm9<<<dim3(1024, 1, 2), 512, 0, stream>>>(X, Y, WTx, WTy, Xhb, Yhb);
  k_gram<<<dim3(P, 1, 3), 512, 0, stream>>>(Xhb, Yhb, part, sx, sy, P);
  k_reduce<<<256, 256, 0, stream>>>(part, sx, sy, Am, Bm, Abf, Bbf, Cbf, CbfT, scal, P);

  k_x1<<<dim3(128, 2), 512, 0, stream>>>(Am, Bm, X0, scal);
  k_it<<<dim3(8, 2), 512, 0, stream>>>(Abf, Bbf, X0, X1);
  k_it<<<dim3(8, 2), 512, 0, stream>>>(Abf, Bbf, X1, X0);
  k_it<<<dim3(8, 2), 512, 0, stream>>>(Abf, Bbf, X0, X1);
  k_it<<<dim3(8, 2), 512, 0, stream>>>(Abf, Bbf, X1, X0);
  k_it<<<dim3(8, 2), 512, 0, stream>>>(Abf, Bbf, X0, X1);   // final in X1
  k_uv<<<dim3(8, 2), 512, 0, stream>>>(X1, Cbf, CbfT, U, V);
  k_fin<<<1, 1024, 0, stream>>>(U, V, scal, out);
}